// Round 2
// baseline (2423.215 us; speedup 1.0000x reference)
//
#include <hip/hip_runtime.h>
#include <stddef.h>

// Problem constants (SSMLayer): B=2, L=2048, DM=1024, DI=2048, N=16, K=4, R=64
#define B_SZ 2
#define L_SZ 2048
#define DM_SZ 1024
#define DI_SZ 2048
#define N_SZ 16
#define K_SZ 4
#define R_SZ 64
#define ROWS (B_SZ * L_SZ)          // 4096

// ---------------------------------------------------------------- rmsnorm ----
// h[row] = x[row] * rsqrt(mean(x^2)+eps) * w ; fp32 in/out
__global__ __launch_bounds__(256) void rmsnorm_kernel(const float* __restrict__ x,
                                                      const float* __restrict__ w,
                                                      float* __restrict__ h) {
    const int row = blockIdx.x;
    const float* xr = x + (size_t)row * DM_SZ;
    const int t4 = threadIdx.x * 4;
    float4 xv = *(const float4*)(xr + t4);
    float ss = xv.x * xv.x + xv.y * xv.y + xv.z * xv.z + xv.w * xv.w;
    #pragma unroll
    for (int off = 32; off; off >>= 1) ss += __shfl_down(ss, off);
    __shared__ float red[4];
    if ((threadIdx.x & 63) == 0) red[threadIdx.x >> 6] = ss;
    __syncthreads();
    float tot = red[0] + red[1] + red[2] + red[3];
    float rs = rsqrtf(tot * (1.0f / DM_SZ) + 1e-5f);
    float4 wv = *(const float4*)(w + t4);
    float4 o;
    o.x = xv.x * rs * wv.x;
    o.y = xv.y * rs * wv.y;
    o.z = xv.z * rs * wv.z;
    o.w = xv.w * rs * wv.w;
    *(float4*)(h + (size_t)row * DM_SZ + t4) = o;
}

// ------------------------------------------------------------------- sgemm ---
// C[M,N] = A[M,K] @ B[K,N] (+ resid), fp32, 64x64 tile, BK=16, 256 thr, 4x4/thr
template <bool HAS_RESID>
__global__ __launch_bounds__(256) void sgemm_f32(const float* __restrict__ A,
                                                 const float* __restrict__ Bm,
                                                 float* __restrict__ C,
                                                 const float* __restrict__ resid,
                                                 int M, int N, int Kd) {
    __shared__ __align__(16) float As[16][68];  // [k][m], padded rows (272B, 16B-mult)
    __shared__ __align__(16) float Bs[16][68];  // [k][n]
    const int bm = blockIdx.y * 64, bn = blockIdx.x * 64;
    const int tid = threadIdx.x;
    const int tx = tid & 15, ty = tid >> 4;
    float acc[4][4] = {};
    for (int k0 = 0; k0 < Kd; k0 += 16) {
        {   // A tile 64x16 (transpose into As[k][m])
            const int row = tid >> 2, kc = (tid & 3) << 2;
            float4 av = *(const float4*)(A + (size_t)(bm + row) * Kd + k0 + kc);
            As[kc + 0][row] = av.x;
            As[kc + 1][row] = av.y;
            As[kc + 2][row] = av.z;
            As[kc + 3][row] = av.w;
        }
        {   // B tile 16x64 (row-contig, aligned float4 store)
            const int kr = tid >> 4, nc = (tid & 15) << 2;
            float4 bv = *(const float4*)(Bm + (size_t)(k0 + kr) * N + bn + nc);
            *(float4*)&Bs[kr][nc] = bv;
        }
        __syncthreads();
        #pragma unroll
        for (int k = 0; k < 16; ++k) {
            float4 a4 = *(const float4*)&As[k][ty << 2];
            float4 b4 = *(const float4*)&Bs[k][tx << 2];
            float ar[4] = {a4.x, a4.y, a4.z, a4.w};
            float br[4] = {b4.x, b4.y, b4.z, b4.w};
            #pragma unroll
            for (int r = 0; r < 4; ++r)
                #pragma unroll
                for (int c = 0; c < 4; ++c) acc[r][c] += ar[r] * br[c];
        }
        __syncthreads();
    }
    #pragma unroll
    for (int r = 0; r < 4; ++r) {
        const int row = bm + (ty << 2) + r;
        const int col = bn + (tx << 2);
        float4 o = make_float4(acc[r][0], acc[r][1], acc[r][2], acc[r][3]);
        if (HAS_RESID) {
            float4 rv = *(const float4*)(resid + (size_t)row * N + col);
            o.x += rv.x; o.y += rv.y; o.z += rv.z; o.w += rv.w;
        }
        *(float4*)(C + (size_t)row * N + col) = o;
    }
}

// -------------------------------------------------------------- conv+silu ---
// u[b,t,d] = silu( sum_k xz[b,t-3+k,d]*cw[d,k] + cb[d] ); xz = first DI cols
__global__ __launch_bounds__(256) void conv_silu_kernel(const float* __restrict__ xz,
                                                        const float* __restrict__ cw,
                                                        const float* __restrict__ cb,
                                                        float* __restrict__ u) {
    const int idx = blockIdx.x * 256 + threadIdx.x;   // over ROWS*DI
    const int d = idx & (DI_SZ - 1);
    const int r = idx >> 11;         // b*L + t
    const int t = r & (L_SZ - 1);
    float4 w4 = *(const float4*)(cw + (d << 2));
    const float w[4] = {w4.x, w4.y, w4.z, w4.w};
    float acc = cb[d];
    const float* base = xz + (size_t)r * (2 * DI_SZ) + d;
    #pragma unroll
    for (int k = 0; k < 4; ++k) {
        int tt = t - 3 + k;
        if (tt >= 0) acc += base[(ptrdiff_t)(k - 3) * (2 * DI_SZ)] * w[k];
    }
    u[idx] = acc / (1.0f + __expf(-acc));
}

// ------------------------------------------------------------------ x_proj ---
// xdbl[ROWS,96] = u[ROWS,2048] @ x_proj_w[2048,96]
__global__ __launch_bounds__(128) void xproj_kernel(const float* __restrict__ u,
                                                    const float* __restrict__ W,
                                                    float* __restrict__ xdbl) {
    const int row0 = blockIdx.x * 16;
    const int tid = threadIdx.x;
    __shared__ float As[16][33];
    const int c = tid;  // output column if < 96
    float acc[16] = {};
    for (int k0 = 0; k0 < DI_SZ; k0 += 32) {
        for (int idx = tid; idx < 16 * 32; idx += 128) {
            int rr = idx >> 5, kk = idx & 31;
            As[rr][kk] = u[(size_t)(row0 + rr) * DI_SZ + k0 + kk];
        }
        __syncthreads();
        if (c < 96) {
            #pragma unroll
            for (int kk = 0; kk < 32; ++kk) {
                float wv = W[(size_t)(k0 + kk) * 96 + c];
                #pragma unroll
                for (int r = 0; r < 16; ++r) acc[r] += As[r][kk] * wv;
            }
        }
        __syncthreads();
    }
    if (c < 96)
        for (int r = 0; r < 16; ++r) xdbl[(size_t)(row0 + r) * 96 + c] = acc[r];
}

// ------------------------------------------------------------ dt_proj+softplus
// dt[ROWS,DI] = softplus(xdbl[:, :64] @ dt_proj_w[64,DI] + b)
__global__ __launch_bounds__(256) void dtproj_kernel(const float* __restrict__ xdbl,
                                                     const float* __restrict__ W,
                                                     const float* __restrict__ bias,
                                                     float* __restrict__ dt) {
    const int col = blockIdx.x * 256 + threadIdx.x;   // d
    const int row0 = blockIdx.y * 8;
    __shared__ float dr[8][64];
    for (int idx = threadIdx.x; idx < 512; idx += 256) {
        int r = idx >> 6, k = idx & 63;
        dr[r][k] = xdbl[(size_t)(row0 + r) * 96 + k];
    }
    __syncthreads();
    float acc[8] = {};
    #pragma unroll 8
    for (int k = 0; k < 64; ++k) {
        float wv = W[(size_t)k * DI_SZ + col];
        #pragma unroll
        for (int r = 0; r < 8; ++r) acc[r] += dr[r][k] * wv;
    }
    const float b = bias[col];
    #pragma unroll
    for (int r = 0; r < 8; ++r) {
        float v = acc[r] + b;
        float sp = (v > 20.0f) ? v : log1pf(__expf(v));
        dt[(size_t)(row0 + r) * DI_SZ + col] = sp;
    }
}

// -------------------------------------------------------------------- scan ---
// Per-channel sequential scan over L; 16 states in registers.
// y[b,t,d] = (sum_n h[n]*C[t,n] + u*D[d]) * silu(z)
__global__ __launch_bounds__(64) void scan_kernel(const float* __restrict__ dt,   // [ROWS,DI]
                                                  const float* __restrict__ u,    // [ROWS,DI]
                                                  const float* __restrict__ xz,   // [ROWS,2*DI] (z at DI+d)
                                                  const float* __restrict__ xdbl, // [ROWS,96]
                                                  const float* __restrict__ A_log,// [DI,16]
                                                  const float* __restrict__ Dw,   // [DI]
                                                  float* __restrict__ y) {        // [ROWS,DI]
    const int b = blockIdx.x >> 5;
    const int d = (blockIdx.x & 31) * 64 + threadIdx.x;
    float A[N_SZ];
    #pragma unroll
    for (int n = 0; n < N_SZ; ++n) A[n] = -expf(A_log[d * N_SZ + n]);
    const float Dd = Dw[d];
    float h[N_SZ] = {};
    __shared__ __align__(16) float bc[64][32];   // B (0..15) and C (16..31) per timestep
    const size_t rbase = (size_t)b * L_SZ;
    for (int t0 = 0; t0 < L_SZ; t0 += 64) {
        __syncthreads();
        for (int idx = threadIdx.x; idx < 64 * 32; idx += 64) {
            int tt = idx >> 5, j = idx & 31;
            bc[tt][j] = xdbl[(rbase + t0 + tt) * 96 + 64 + j];
        }
        __syncthreads();
        for (int ti = 0; ti < 64; ++ti) {
            const size_t r = rbase + t0 + ti;
            const float dtv = dt[r * DI_SZ + d];
            const float uv = u[r * DI_SZ + d];
            const float zv = xz[r * (2 * DI_SZ) + DI_SZ + d];
            float bcv[32];
            #pragma unroll
            for (int q = 0; q < 8; ++q) *(float4*)&bcv[q * 4] = ((const float4*)&bc[ti][0])[q];
            const float dtu = dtv * uv;
            float yv = 0.0f;
            #pragma unroll
            for (int n = 0; n < N_SZ; ++n) {
                float dA = __expf(dtv * A[n]);
                h[n] = dA * h[n] + dtu * bcv[n];
                yv += h[n] * bcv[16 + n];
            }
            const float sz = zv / (1.0f + __expf(-zv));
            y[r * DI_SZ + d] = (yv + uv * Dd) * sz;
        }
    }
}

// ---------------------------------------------------------------- launcher ---
extern "C" void kernel_launch(void* const* d_in, const int* in_sizes, int n_in,
                              void* d_out, int out_size, void* d_ws, size_t ws_size,
                              hipStream_t stream) {
    const float* x         = (const float*)d_in[0];
    // d_in[1] hormone_vectors: unused by reference
    const float* norm_w    = (const float*)d_in[2];
    const float* in_proj_w = (const float*)d_in[3];
    const float* conv_w    = (const float*)d_in[4];
    const float* conv_b    = (const float*)d_in[5];
    const float* x_proj_w  = (const float*)d_in[6];
    const float* dt_proj_w = (const float*)d_in[7];
    const float* dt_proj_b = (const float*)d_in[8];
    const float* A_log     = (const float*)d_in[9];
    const float* Dw        = (const float*)d_in[10];
    const float* out_proj_w= (const float*)d_in[11];
    float* out = (float*)d_out;

    // Workspace layout (fp32). y aliases h's region: h is dead after GEMM1,
    // y is written first at the scan. Region sized for the larger (y).
    char* ws = (char*)d_ws;
    size_t off = 0;
    float* y    = (float*)(ws + off);  off += (size_t)ROWS * DI_SZ * 4;       // 33.5 MB (h shares)
    float* h    = y;                                                          // [ROWS,DM] ⊂ region
    float* xz   = (float*)(ws + off);  off += (size_t)ROWS * 2 * DI_SZ * 4;   // 67.1 MB
    float* u    = (float*)(ws + off);  off += (size_t)ROWS * DI_SZ * 4;       // 33.5 MB
    float* xdbl = (float*)(ws + off);  off += (size_t)ROWS * 96 * 4;          // 1.6 MB
    float* dt   = (float*)(ws + off);  off += (size_t)ROWS * DI_SZ * 4;       // 33.5 MB
    (void)ws_size; (void)out_size; (void)n_in; (void)in_sizes;

    // 1. rmsnorm
    rmsnorm_kernel<<<ROWS, 256, 0, stream>>>(x, norm_w, h);
    // 2. xz = h @ in_proj_w   (4096 x 4096 x 1024)
    sgemm_f32<false><<<dim3(2 * DI_SZ / 64, ROWS / 64), 256, 0, stream>>>(
        h, in_proj_w, xz, nullptr, ROWS, 2 * DI_SZ, DM_SZ);
    // 3. u = silu(conv(xz[:, :DI]))
    conv_silu_kernel<<<(ROWS * DI_SZ) / 256, 256, 0, stream>>>(xz, conv_w, conv_b, u);
    // 4. xdbl = u @ x_proj_w  (4096 x 96 x 2048)
    xproj_kernel<<<ROWS / 16, 128, 0, stream>>>(u, x_proj_w, xdbl);
    // 5. dt = softplus(xdbl[:, :64] @ dt_proj_w + b)
    dtproj_kernel<<<dim3(DI_SZ / 256, ROWS / 8), 256, 0, stream>>>(xdbl, dt_proj_w, dt_proj_b, dt);
    // 6. selective scan -> y  (overwrites h's region; h is dead)
    scan_kernel<<<B_SZ * (DI_SZ / 64), 64, 0, stream>>>(dt, u, xz, xdbl, A_log, Dw, y);
    // 7. out = x + y @ out_proj_w  (4096 x 1024 x 2048)
    sgemm_f32<true><<<dim3(DM_SZ / 64, ROWS / 64), 256, 0, stream>>>(
        y, out_proj_w, out, x, ROWS, DM_SZ, DI_SZ);
}

// Round 3
// 1259.193 us; speedup vs baseline: 1.9244x; 1.9244x over previous
//
#include <hip/hip_runtime.h>
#include <stddef.h>

// Problem constants (SSMLayer): B=2, L=2048, DM=1024, DI=2048, N=16, K=4, R=64
#define B_SZ 2
#define L_SZ 2048
#define DM_SZ 1024
#define DI_SZ 2048
#define N_SZ 16
#define K_SZ 4
#define R_SZ 64
#define ROWS (B_SZ * L_SZ)          // 4096
#define CH 32                       // scan chunk length
#define NCH (L_SZ / CH)             // 64 chunks
#define PS_SLICE (B_SZ * DI_SZ * N_SZ)   // 65536 floats per chunk slice

// ---------------------------------------------------------------- rmsnorm ----
__global__ __launch_bounds__(256) void rmsnorm_kernel(const float* __restrict__ x,
                                                      const float* __restrict__ w,
                                                      float* __restrict__ h) {
    const int row = blockIdx.x;
    const float* xr = x + (size_t)row * DM_SZ;
    const int t4 = threadIdx.x * 4;
    float4 xv = *(const float4*)(xr + t4);
    float ss = xv.x * xv.x + xv.y * xv.y + xv.z * xv.z + xv.w * xv.w;
    #pragma unroll
    for (int off = 32; off; off >>= 1) ss += __shfl_down(ss, off);
    __shared__ float red[4];
    if ((threadIdx.x & 63) == 0) red[threadIdx.x >> 6] = ss;
    __syncthreads();
    float tot = red[0] + red[1] + red[2] + red[3];
    float rs = rsqrtf(tot * (1.0f / DM_SZ) + 1e-5f);
    float4 wv = *(const float4*)(w + t4);
    float4 o;
    o.x = xv.x * rs * wv.x;
    o.y = xv.y * rs * wv.y;
    o.z = xv.z * rs * wv.z;
    o.w = xv.w * rs * wv.w;
    *(float4*)(h + (size_t)row * DM_SZ + t4) = o;
}

// ------------------------------------------------------------------- sgemm ---
// C[M,N] = A[M,K] @ B[K,N] (+ resid), fp32, 64x64 tile, BK=16, 256 thr, 4x4/thr
template <bool HAS_RESID>
__global__ __launch_bounds__(256) void sgemm_f32(const float* __restrict__ A,
                                                 const float* __restrict__ Bm,
                                                 float* __restrict__ C,
                                                 const float* __restrict__ resid,
                                                 int M, int N, int Kd) {
    __shared__ __align__(16) float As[16][68];
    __shared__ __align__(16) float Bs[16][68];
    const int bm = blockIdx.y * 64, bn = blockIdx.x * 64;
    const int tid = threadIdx.x;
    const int tx = tid & 15, ty = tid >> 4;
    float acc[4][4] = {};
    for (int k0 = 0; k0 < Kd; k0 += 16) {
        {   // A tile 64x16 (transpose into As[k][m])
            const int row = tid >> 2, kc = (tid & 3) << 2;
            float4 av = *(const float4*)(A + (size_t)(bm + row) * Kd + k0 + kc);
            As[kc + 0][row] = av.x;
            As[kc + 1][row] = av.y;
            As[kc + 2][row] = av.z;
            As[kc + 3][row] = av.w;
        }
        {   // B tile 16x64
            const int kr = tid >> 4, nc = (tid & 15) << 2;
            float4 bv = *(const float4*)(Bm + (size_t)(k0 + kr) * N + bn + nc);
            *(float4*)&Bs[kr][nc] = bv;
        }
        __syncthreads();
        #pragma unroll
        for (int k = 0; k < 16; ++k) {
            float4 a4 = *(const float4*)&As[k][ty << 2];
            float4 b4 = *(const float4*)&Bs[k][tx << 2];
            float ar[4] = {a4.x, a4.y, a4.z, a4.w};
            float br[4] = {b4.x, b4.y, b4.z, b4.w};
            #pragma unroll
            for (int r = 0; r < 4; ++r)
                #pragma unroll
                for (int c = 0; c < 4; ++c) acc[r][c] += ar[r] * br[c];
        }
        __syncthreads();
    }
    #pragma unroll
    for (int r = 0; r < 4; ++r) {
        const int row = bm + (ty << 2) + r;
        const int col = bn + (tx << 2);
        float4 o = make_float4(acc[r][0], acc[r][1], acc[r][2], acc[r][3]);
        if (HAS_RESID) {
            float4 rv = *(const float4*)(resid + (size_t)row * N + col);
            o.x += rv.x; o.y += rv.y; o.z += rv.z; o.w += rv.w;
        }
        *(float4*)(C + (size_t)row * N + col) = o;
    }
}

// -------------------------------------------------------------- conv+silu ---
__global__ __launch_bounds__(256) void conv_silu_kernel(const float* __restrict__ xz,
                                                        const float* __restrict__ cw,
                                                        const float* __restrict__ cb,
                                                        float* __restrict__ u) {
    const int idx = blockIdx.x * 256 + threadIdx.x;   // over ROWS*DI
    const int d = idx & (DI_SZ - 1);
    const int r = idx >> 11;         // b*L + t
    const int t = r & (L_SZ - 1);
    float4 w4 = *(const float4*)(cw + (d << 2));
    const float w[4] = {w4.x, w4.y, w4.z, w4.w};
    float acc = cb[d];
    const float* base = xz + (size_t)r * (2 * DI_SZ) + d;
    #pragma unroll
    for (int k = 0; k < 4; ++k) {
        int tt = t - 3 + k;
        if (tt >= 0) acc += base[(ptrdiff_t)(k - 3) * (2 * DI_SZ)] * w[k];
    }
    u[idx] = acc / (1.0f + __expf(-acc));
}

// ------------------------------------------------------------------ x_proj ---
__global__ __launch_bounds__(128) void xproj_kernel(const float* __restrict__ u,
                                                    const float* __restrict__ W,
                                                    float* __restrict__ xdbl) {
    const int row0 = blockIdx.x * 16;
    const int tid = threadIdx.x;
    __shared__ float As[16][33];
    const int c = tid;
    float acc[16] = {};
    for (int k0 = 0; k0 < DI_SZ; k0 += 32) {
        for (int idx = tid; idx < 16 * 32; idx += 128) {
            int rr = idx >> 5, kk = idx & 31;
            As[rr][kk] = u[(size_t)(row0 + rr) * DI_SZ + k0 + kk];
        }
        __syncthreads();
        if (c < 96) {
            #pragma unroll
            for (int kk = 0; kk < 32; ++kk) {
                float wv = W[(size_t)(k0 + kk) * 96 + c];
                #pragma unroll
                for (int r = 0; r < 16; ++r) acc[r] += As[r][kk] * wv;
            }
        }
        __syncthreads();
    }
    if (c < 96)
        for (int r = 0; r < 16; ++r) xdbl[(size_t)(row0 + r) * 96 + c] = acc[r];
}

// ------------------------------------------------------------ dt_proj+softplus
__global__ __launch_bounds__(256) void dtproj_kernel(const float* __restrict__ xdbl,
                                                     const float* __restrict__ W,
                                                     const float* __restrict__ bias,
                                                     float* __restrict__ dt) {
    const int col = blockIdx.x * 256 + threadIdx.x;   // d
    const int row0 = blockIdx.y * 8;
    __shared__ float dr[8][64];
    for (int idx = threadIdx.x; idx < 512; idx += 256) {
        int r = idx >> 6, k = idx & 63;
        dr[r][k] = xdbl[(size_t)(row0 + r) * 96 + k];
    }
    __syncthreads();
    float acc[8] = {};
    #pragma unroll 8
    for (int k = 0; k < 64; ++k) {
        float wv = W[(size_t)k * DI_SZ + col];
        #pragma unroll
        for (int r = 0; r < 8; ++r) acc[r] += dr[r][k] * wv;
    }
    const float b = bias[col];
    #pragma unroll
    for (int r = 0; r < 8; ++r) {
        float v = acc[r] + b;
        float sp = (v > 20.0f) ? v : log1pf(__expf(v));
        dt[(size_t)(row0 + r) * DI_SZ + col] = sp;
    }
}

// ------------------------------------------------- scan pass 1: local chunks -
// For chunk c of channel d: P[n] = prod dA, S[n] = local end state (h0 = 0).
// Layout P/S: [c][b][d][n] flat.
__global__ __launch_bounds__(64) void scan_pass1(const float* __restrict__ dt,
                                                 const float* __restrict__ u,
                                                 const float* __restrict__ xdbl,
                                                 const float* __restrict__ A_log,
                                                 float* __restrict__ P,
                                                 float* __restrict__ S) {
    const int c     = blockIdx.x & (NCH - 1);
    const int dtile = (blockIdx.x >> 6) & 31;
    const int b     = blockIdx.x >> 11;
    const int d     = dtile * 64 + threadIdx.x;
    float A[N_SZ];
    #pragma unroll
    for (int n = 0; n < N_SZ; ++n) A[n] = -expf(A_log[d * N_SZ + n]);
    __shared__ __align__(16) float bs[CH][16];
    const size_t rbase = (size_t)b * L_SZ + c * CH;
    for (int idx = threadIdx.x; idx < CH * 16; idx += 64) {
        int tt = idx >> 4, j = idx & 15;
        bs[tt][j] = xdbl[(rbase + tt) * 96 + 64 + j];
    }
    __syncthreads();
    float h[N_SZ] = {};
    float p[N_SZ];
    #pragma unroll
    for (int n = 0; n < N_SZ; ++n) p[n] = 1.0f;
    float dtv = dt[rbase * DI_SZ + d];
    float uv  = u[rbase * DI_SZ + d];
    for (int ti = 0; ti < CH; ++ti) {
        float dtn = 0.0f, un = 0.0f;
        if (ti + 1 < CH) {   // prefetch next step
            dtn = dt[(rbase + ti + 1) * DI_SZ + d];
            un  = u[(rbase + ti + 1) * DI_SZ + d];
        }
        const float dtu = dtv * uv;
        float bv[N_SZ];
        #pragma unroll
        for (int q = 0; q < 4; ++q) *(float4*)&bv[q * 4] = *(const float4*)&bs[ti][q * 4];
        #pragma unroll
        for (int n = 0; n < N_SZ; ++n) {
            float dA = __expf(dtv * A[n]);
            p[n] *= dA;
            h[n] = dA * h[n] + dtu * bv[n];
        }
        dtv = dtn; uv = un;
    }
    const size_t base = (size_t)c * PS_SLICE + ((size_t)b * DI_SZ + d) * N_SZ;
    #pragma unroll
    for (int q = 0; q < 4; ++q) {
        *(float4*)&P[base + q * 4] = make_float4(p[q*4], p[q*4+1], p[q*4+2], p[q*4+3]);
        *(float4*)&S[base + q * 4] = make_float4(h[q*4], h[q*4+1], h[q*4+2], h[q*4+3]);
    }
}

// --------------------------------------- scan pass 2: scan over chunks ------
// Each thread owns one (b,d,n). S[c] is replaced in-place by the state at the
// START of chunk c; recurrence h = P[c]*h + S[c] carries across chunks.
__global__ __launch_bounds__(256) void scan_pass2(float* __restrict__ P,
                                                  float* __restrict__ S) {
    const int i = blockIdx.x * 256 + threadIdx.x;   // [0, PS_SLICE)
    float h = 0.0f;
    for (int c = 0; c < NCH; ++c) {
        const size_t idx = (size_t)c * PS_SLICE + i;
        const float p = P[idx];
        const float s = S[idx];
        S[idx] = h;
        h = p * h + s;
    }
}

// ----------------------------------- scan pass 3: replay with correct h0 ----
__global__ __launch_bounds__(64) void scan_pass3(const float* __restrict__ dt,
                                                 const float* __restrict__ u,
                                                 const float* __restrict__ xz,
                                                 const float* __restrict__ xdbl,
                                                 const float* __restrict__ A_log,
                                                 const float* __restrict__ Dw,
                                                 const float* __restrict__ H0,
                                                 float* __restrict__ y) {
    const int c     = blockIdx.x & (NCH - 1);
    const int dtile = (blockIdx.x >> 6) & 31;
    const int b     = blockIdx.x >> 11;
    const int d     = dtile * 64 + threadIdx.x;
    float A[N_SZ];
    #pragma unroll
    for (int n = 0; n < N_SZ; ++n) A[n] = -expf(A_log[d * N_SZ + n]);
    const float Dd = Dw[d];
    __shared__ __align__(16) float bc[CH][32];   // B (0..15) | C (16..31)
    const size_t rbase = (size_t)b * L_SZ + c * CH;
    for (int idx = threadIdx.x; idx < CH * 32; idx += 64) {
        int tt = idx >> 5, j = idx & 31;
        bc[tt][j] = xdbl[(rbase + tt) * 96 + 64 + j];
    }
    __syncthreads();
    float h[N_SZ];
    const size_t hbase = (size_t)c * PS_SLICE + ((size_t)b * DI_SZ + d) * N_SZ;
    #pragma unroll
    for (int q = 0; q < 4; ++q) *(float4*)&h[q * 4] = *(const float4*)&H0[hbase + q * 4];
    float dtv = dt[rbase * DI_SZ + d];
    float uv  = u[rbase * DI_SZ + d];
    float zv  = xz[rbase * (2 * DI_SZ) + DI_SZ + d];
    for (int ti = 0; ti < CH; ++ti) {
        float dtn = 0.0f, un = 0.0f, zn = 0.0f;
        if (ti + 1 < CH) {   // prefetch next step
            const size_t rn = rbase + ti + 1;
            dtn = dt[rn * DI_SZ + d];
            un  = u[rn * DI_SZ + d];
            zn  = xz[rn * (2 * DI_SZ) + DI_SZ + d];
        }
        const float dtu = dtv * uv;
        float bv[32];
        #pragma unroll
        for (int q = 0; q < 8; ++q) *(float4*)&bv[q * 4] = *(const float4*)&bc[ti][q * 4];
        float yv = 0.0f;
        #pragma unroll
        for (int n = 0; n < N_SZ; ++n) {
            float dA = __expf(dtv * A[n]);
            h[n] = dA * h[n] + dtu * bv[n];
            yv += h[n] * bv[16 + n];
        }
        const float sz = zv / (1.0f + __expf(-zv));
        y[(rbase + ti) * DI_SZ + d] = (yv + uv * Dd) * sz;
        dtv = dtn; uv = un; zv = zn;
    }
}

// ---------------------------------------------------------------- launcher ---
extern "C" void kernel_launch(void* const* d_in, const int* in_sizes, int n_in,
                              void* d_out, int out_size, void* d_ws, size_t ws_size,
                              hipStream_t stream) {
    const float* x         = (const float*)d_in[0];
    // d_in[1] hormone_vectors: unused by reference
    const float* norm_w    = (const float*)d_in[2];
    const float* in_proj_w = (const float*)d_in[3];
    const float* conv_w    = (const float*)d_in[4];
    const float* conv_b    = (const float*)d_in[5];
    const float* x_proj_w  = (const float*)d_in[6];
    const float* dt_proj_w = (const float*)d_in[7];
    const float* dt_proj_b = (const float*)d_in[8];
    const float* A_log     = (const float*)d_in[9];
    const float* Dw        = (const float*)d_in[10];
    const float* out_proj_w= (const float*)d_in[11];
    float* out = (float*)d_out;

    char* ws = (char*)d_ws;
    size_t off = 0;
    float* y    = (float*)(ws + off);  off += (size_t)ROWS * DI_SZ * 4;       // 33.5 MB (h aliases)
    float* h    = y;                                                          // [ROWS,DM] ⊂ region
    float* xz   = (float*)(ws + off);  off += (size_t)ROWS * 2 * DI_SZ * 4;   // 67.1 MB
    float* u    = (float*)(ws + off);  off += (size_t)ROWS * DI_SZ * 4;       // 33.5 MB
    float* xdbl = (float*)(ws + off);  off += (size_t)ROWS * 96 * 4;          // 1.6 MB
    float* dt   = (float*)(ws + off);  off += (size_t)ROWS * DI_SZ * 4;       // 33.5 MB
    float* P    = (float*)(ws + off);  off += (size_t)NCH * PS_SLICE * 4;     // 16.8 MB
    float* S    = (float*)(ws + off);  off += (size_t)NCH * PS_SLICE * 4;     // 16.8 MB
    (void)ws_size; (void)out_size; (void)n_in; (void)in_sizes;

    // 1. rmsnorm
    rmsnorm_kernel<<<ROWS, 256, 0, stream>>>(x, norm_w, h);
    // 2. xz = h @ in_proj_w   (4096 x 4096 x 1024)
    sgemm_f32<false><<<dim3(2 * DI_SZ / 64, ROWS / 64), 256, 0, stream>>>(
        h, in_proj_w, xz, nullptr, ROWS, 2 * DI_SZ, DM_SZ);
    // 3. u = silu(conv(xz[:, :DI]))
    conv_silu_kernel<<<(ROWS * DI_SZ) / 256, 256, 0, stream>>>(xz, conv_w, conv_b, u);
    // 4. xdbl = u @ x_proj_w  (4096 x 96 x 2048)
    xproj_kernel<<<ROWS / 16, 128, 0, stream>>>(u, x_proj_w, xdbl);
    // 5. dt = softplus(xdbl[:, :64] @ dt_proj_w + b)
    dtproj_kernel<<<dim3(DI_SZ / 256, ROWS / 8), 256, 0, stream>>>(xdbl, dt_proj_w, dt_proj_b, dt);
    // 6. chunked selective scan -> y
    scan_pass1<<<B_SZ * 32 * NCH, 64, 0, stream>>>(dt, u, xdbl, A_log, P, S);
    scan_pass2<<<PS_SLICE / 256, 256, 0, stream>>>(P, S);
    scan_pass3<<<B_SZ * 32 * NCH, 64, 0, stream>>>(dt, u, xz, xdbl, A_log, Dw, S, y);
    // 7. out = x + y @ out_proj_w  (4096 x 1024 x 2048)
    sgemm_f32<true><<<dim3(DM_SZ / 64, ROWS / 64), 256, 0, stream>>>(
        y, out_proj_w, out, x, ROWS, DM_SZ, DI_SZ);
}

// Round 4
// 697.723 us; speedup vs baseline: 3.4730x; 1.8047x over previous
//
#include <hip/hip_runtime.h>
#include <stddef.h>

// Problem constants (SSMLayer): B=2, L=2048, DM=1024, DI=2048, N=16, K=4, R=64
#define B_SZ 2
#define L_SZ 2048
#define DM_SZ 1024
#define DI_SZ 2048
#define N_SZ 16
#define K_SZ 4
#define R_SZ 64
#define ROWS (B_SZ * L_SZ)          // 4096
#define CH 32                       // scan chunk length
#define NCH (L_SZ / CH)             // 64 chunks
#define PS_SLICE (B_SZ * DI_SZ * N_SZ)   // 65536 floats per chunk slice

typedef unsigned short u16;
typedef unsigned int u32;
typedef short bf16x8 __attribute__((ext_vector_type(8)));
typedef float f32x4 __attribute__((ext_vector_type(4)));

__device__ __forceinline__ u16 f2bf(float f) {
    union { float f; u32 i; } v; v.f = f;
    u32 x = v.i;
    return (u16)((x + 0x7FFFu + ((x >> 16) & 1u)) >> 16);   // RNE
}

__device__ __forceinline__ void gload_lds16(const void* g, void* l) {
    __builtin_amdgcn_global_load_lds((const __attribute__((address_space(1))) u32*)g,
                                     (__attribute__((address_space(3))) u32*)l, 16, 0, 0);
}

// ---------------------------------------------------------------- rmsnorm ----
// h[row] = bf16( x[row] * rsqrt(mean(x^2)+eps) * w )
__global__ __launch_bounds__(256) void rmsnorm_kernel(const float* __restrict__ x,
                                                      const float* __restrict__ w,
                                                      u16* __restrict__ h) {
    const int row = blockIdx.x;
    const float* xr = x + (size_t)row * DM_SZ;
    const int t4 = threadIdx.x * 4;
    float4 xv = *(const float4*)(xr + t4);
    float ss = xv.x * xv.x + xv.y * xv.y + xv.z * xv.z + xv.w * xv.w;
    #pragma unroll
    for (int off = 32; off; off >>= 1) ss += __shfl_down(ss, off);
    __shared__ float red[4];
    if ((threadIdx.x & 63) == 0) red[threadIdx.x >> 6] = ss;
    __syncthreads();
    float tot = red[0] + red[1] + red[2] + red[3];
    float rs = rsqrtf(tot * (1.0f / DM_SZ) + 1e-5f);
    float4 wv = *(const float4*)(w + t4);
    ushort4 o;
    o.x = f2bf(xv.x * rs * wv.x);
    o.y = f2bf(xv.y * rs * wv.y);
    o.z = f2bf(xv.z * rs * wv.z);
    o.w = f2bf(xv.w * rs * wv.w);
    *(ushort4*)(h + (size_t)row * DM_SZ + t4) = o;
}

// ---------------------------------------------- transpose + fp32->bf16 ------
// Wt[n][k] = bf16(W[k][n]); K, N multiples of 32. grid (N/32, K/32), 256 thr.
__global__ __launch_bounds__(256) void transpose_bf16_kernel(const float* __restrict__ W,
                                                             u16* __restrict__ Wt,
                                                             int K, int N) {
    __shared__ float t[32][33];
    const int n0 = blockIdx.x * 32, k0 = blockIdx.y * 32;
    const int tx = threadIdx.x & 31, ty = threadIdx.x >> 5;   // ty in [0,8)
    #pragma unroll
    for (int p = 0; p < 4; ++p)
        t[ty + p * 8][tx] = W[(size_t)(k0 + ty + p * 8) * N + n0 + tx];
    __syncthreads();
    #pragma unroll
    for (int p = 0; p < 4; ++p)
        Wt[(size_t)(n0 + ty + p * 8) * K + k0 + tx] = f2bf(t[tx][ty + p * 8]);
}

// ---------------------------------------------------------------- mfma gemm --
// C[M,N] = A[M,K] @ Bt[N,K]^T (+resid), A/Bt bf16 row-major, C fp32.
// 128x128 tile, BK=32, 256 threads = 4 waves, wave = 4x4 grid of 16x16x32 MFMA.
template <bool HAS_RESID>
__global__ __launch_bounds__(256, 2) void mfma_gemm_bt(const u16* __restrict__ A,
                                                       const u16* __restrict__ Bt,
                                                       float* __restrict__ C,
                                                       const float* __restrict__ resid,
                                                       int M, int N, int Kd) {
    __shared__ __align__(16) u16 As[128 * 32];   // [m][k], 8 KB
    __shared__ __align__(16) u16 Bs[128 * 32];   // [n][k], 8 KB
    const int tid = threadIdx.x;
    const int lane = tid & 63;
    const int w = tid >> 6;
    const int wm = w >> 1, wn = w & 1;
    const int bm = blockIdx.y * 128, bn = blockIdx.x * 128;

    // staging: wave w, instr q in {0,1}: 16 rows of the tile, lane L -> row
    // (w*2+q)*16 + (L>>2), 16-B chunk (L&3). LDS dst = base + L*16 (HW rule).
    const int r0 = (w * 2 + 0) * 16 + (lane >> 2);
    const int r1 = (w * 2 + 1) * 16 + (lane >> 2);
    const int kc = (lane & 3) * 8;
    const u16* Aq0 = A + (size_t)(bm + r0) * Kd + kc;
    const u16* Aq1 = A + (size_t)(bm + r1) * Kd + kc;
    const u16* Bq0 = Bt + (size_t)(bn + r0) * Kd + kc;
    const u16* Bq1 = Bt + (size_t)(bn + r1) * Kd + kc;
    u16* lA0 = As + (w * 2 + 0) * 512;
    u16* lA1 = As + (w * 2 + 1) * 512;
    u16* lB0 = Bs + (w * 2 + 0) * 512;
    u16* lB1 = Bs + (w * 2 + 1) * 512;

    f32x4 acc[4][4] = {};
    const int fm = (lane & 15);          // m (resp. n) within 16-tile
    const int q8 = (lane >> 4) * 8;      // k offset of this lane's 8 elems

    for (int k0 = 0; k0 < Kd; k0 += 32) {
        gload_lds16(Aq0 + k0, lA0);
        gload_lds16(Aq1 + k0, lA1);
        gload_lds16(Bq0 + k0, lB0);
        gload_lds16(Bq1 + k0, lB1);
        __syncthreads();   // drains vmcnt -> tiles visible
        bf16x8 af[4], bf[4];
        #pragma unroll
        for (int i = 0; i < 4; ++i)
            af[i] = *(const bf16x8*)&As[(wm * 64 + i * 16 + fm) * 32 + q8];
        #pragma unroll
        for (int j = 0; j < 4; ++j)
            bf[j] = *(const bf16x8*)&Bs[(wn * 64 + j * 16 + fm) * 32 + q8];
        #pragma unroll
        for (int i = 0; i < 4; ++i)
            #pragma unroll
            for (int j = 0; j < 4; ++j)
                acc[i][j] = __builtin_amdgcn_mfma_f32_16x16x32_bf16(af[i], bf[j], acc[i][j], 0, 0, 0);
        __syncthreads();   // protect LDS before next stage
    }

    // epilogue: D reg r -> row (lane>>4)*4 + r, col lane&15
    const int crow0 = bm + wm * 64 + (lane >> 4) * 4;
    const int ccol0 = bn + wn * 64 + (lane & 15);
    #pragma unroll
    for (int i = 0; i < 4; ++i) {
        #pragma unroll
        for (int r = 0; r < 4; ++r) {
            const int row = crow0 + i * 16 + r;
            #pragma unroll
            for (int j = 0; j < 4; ++j) {
                const int col = ccol0 + j * 16;
                float v = acc[i][j][r];
                if (HAS_RESID) v += resid[(size_t)row * N + col];
                C[(size_t)row * N + col] = v;
            }
        }
    }
}

// -------------------------------------------------------------- conv+silu ---
__global__ __launch_bounds__(256) void conv_silu_kernel(const float* __restrict__ xz,
                                                        const float* __restrict__ cw,
                                                        const float* __restrict__ cb,
                                                        float* __restrict__ u) {
    const int idx = blockIdx.x * 256 + threadIdx.x;   // over ROWS*DI
    const int d = idx & (DI_SZ - 1);
    const int r = idx >> 11;         // b*L + t
    const int t = r & (L_SZ - 1);
    float4 w4 = *(const float4*)(cw + (d << 2));
    const float w[4] = {w4.x, w4.y, w4.z, w4.w};
    float acc = cb[d];
    const float* base = xz + (size_t)r * (2 * DI_SZ) + d;
    #pragma unroll
    for (int k = 0; k < 4; ++k) {
        int tt = t - 3 + k;
        if (tt >= 0) acc += base[(ptrdiff_t)(k - 3) * (2 * DI_SZ)] * w[k];
    }
    u[idx] = acc / (1.0f + __expf(-acc));
}

// ------------------------------------------------------------------ x_proj ---
__global__ __launch_bounds__(128) void xproj_kernel(const float* __restrict__ u,
                                                    const float* __restrict__ W,
                                                    float* __restrict__ xdbl) {
    const int row0 = blockIdx.x * 16;
    const int tid = threadIdx.x;
    __shared__ float As[16][33];
    const int c = tid;
    float acc[16] = {};
    for (int k0 = 0; k0 < DI_SZ; k0 += 32) {
        for (int idx = tid; idx < 16 * 32; idx += 128) {
            int rr = idx >> 5, kk = idx & 31;
            As[rr][kk] = u[(size_t)(row0 + rr) * DI_SZ + k0 + kk];
        }
        __syncthreads();
        if (c < 96) {
            #pragma unroll
            for (int kk = 0; kk < 32; ++kk) {
                float wv = W[(size_t)(k0 + kk) * 96 + c];
                #pragma unroll
                for (int r = 0; r < 16; ++r) acc[r] += As[r][kk] * wv;
            }
        }
        __syncthreads();
    }
    if (c < 96)
        for (int r = 0; r < 16; ++r) xdbl[(size_t)(row0 + r) * 96 + c] = acc[r];
}

// ------------------------------------------------------------ dt_proj+softplus
__global__ __launch_bounds__(256) void dtproj_kernel(const float* __restrict__ xdbl,
                                                     const float* __restrict__ W,
                                                     const float* __restrict__ bias,
                                                     float* __restrict__ dt) {
    const int col = blockIdx.x * 256 + threadIdx.x;   // d
    const int row0 = blockIdx.y * 8;
    __shared__ float dr[8][64];
    for (int idx = threadIdx.x; idx < 512; idx += 256) {
        int r = idx >> 6, k = idx & 63;
        dr[r][k] = xdbl[(size_t)(row0 + r) * 96 + k];
    }
    __syncthreads();
    float acc[8] = {};
    #pragma unroll 8
    for (int k = 0; k < 64; ++k) {
        float wv = W[(size_t)k * DI_SZ + col];
        #pragma unroll
        for (int r = 0; r < 8; ++r) acc[r] += dr[r][k] * wv;
    }
    const float b = bias[col];
    #pragma unroll
    for (int r = 0; r < 8; ++r) {
        float v = acc[r] + b;
        float sp = (v > 20.0f) ? v : log1pf(__expf(v));
        dt[(size_t)(row0 + r) * DI_SZ + col] = sp;
    }
}

// ------------------------------------------------- scan pass 1: local chunks -
__global__ __launch_bounds__(64) void scan_pass1(const float* __restrict__ dt,
                                                 const float* __restrict__ u,
                                                 const float* __restrict__ xdbl,
                                                 const float* __restrict__ A_log,
                                                 float* __restrict__ P,
                                                 float* __restrict__ S) {
    const int c     = blockIdx.x & (NCH - 1);
    const int dtile = (blockIdx.x >> 6) & 31;
    const int b     = blockIdx.x >> 11;
    const int d     = dtile * 64 + threadIdx.x;
    float A[N_SZ];
    #pragma unroll
    for (int n = 0; n < N_SZ; ++n) A[n] = -expf(A_log[d * N_SZ + n]);
    __shared__ __align__(16) float bs[CH][16];
    const size_t rbase = (size_t)b * L_SZ + c * CH;
    for (int idx = threadIdx.x; idx < CH * 16; idx += 64) {
        int tt = idx >> 4, j = idx & 15;
        bs[tt][j] = xdbl[(rbase + tt) * 96 + 64 + j];
    }
    __syncthreads();
    float h[N_SZ] = {};
    float p[N_SZ];
    #pragma unroll
    for (int n = 0; n < N_SZ; ++n) p[n] = 1.0f;
    float dtv = dt[rbase * DI_SZ + d];
    float uv  = u[rbase * DI_SZ + d];
    for (int ti = 0; ti < CH; ++ti) {
        float dtn = 0.0f, un = 0.0f;
        if (ti + 1 < CH) {
            dtn = dt[(rbase + ti + 1) * DI_SZ + d];
            un  = u[(rbase + ti + 1) * DI_SZ + d];
        }
        const float dtu = dtv * uv;
        float bv[N_SZ];
        #pragma unroll
        for (int q = 0; q < 4; ++q) *(float4*)&bv[q * 4] = *(const float4*)&bs[ti][q * 4];
        #pragma unroll
        for (int n = 0; n < N_SZ; ++n) {
            float dA = __expf(dtv * A[n]);
            p[n] *= dA;
            h[n] = dA * h[n] + dtu * bv[n];
        }
        dtv = dtn; uv = un;
    }
    const size_t base = (size_t)c * PS_SLICE + ((size_t)b * DI_SZ + d) * N_SZ;
    #pragma unroll
    for (int q = 0; q < 4; ++q) {
        *(float4*)&P[base + q * 4] = make_float4(p[q*4], p[q*4+1], p[q*4+2], p[q*4+3]);
        *(float4*)&S[base + q * 4] = make_float4(h[q*4], h[q*4+1], h[q*4+2], h[q*4+3]);
    }
}

// --------------------------------------- scan pass 2: scan over chunks ------
__global__ __launch_bounds__(256) void scan_pass2(float* __restrict__ P,
                                                  float* __restrict__ S) {
    const int i = blockIdx.x * 256 + threadIdx.x;   // [0, PS_SLICE)
    float h = 0.0f;
    for (int c = 0; c < NCH; ++c) {
        const size_t idx = (size_t)c * PS_SLICE + i;
        const float p = P[idx];
        const float s = S[idx];
        S[idx] = h;
        h = p * h + s;
    }
}

// ----------------------------------- scan pass 3: replay with correct h0 ----
// y emitted in bf16 (A-operand of the output GEMM).
__global__ __launch_bounds__(64) void scan_pass3(const float* __restrict__ dt,
                                                 const float* __restrict__ u,
                                                 const float* __restrict__ xz,
                                                 const float* __restrict__ xdbl,
                                                 const float* __restrict__ A_log,
                                                 const float* __restrict__ Dw,
                                                 const float* __restrict__ H0,
                                                 u16* __restrict__ y) {
    const int c     = blockIdx.x & (NCH - 1);
    const int dtile = (blockIdx.x >> 6) & 31;
    const int b     = blockIdx.x >> 11;
    const int d     = dtile * 64 + threadIdx.x;
    float A[N_SZ];
    #pragma unroll
    for (int n = 0; n < N_SZ; ++n) A[n] = -expf(A_log[d * N_SZ + n]);
    const float Dd = Dw[d];
    __shared__ __align__(16) float bc[CH][32];   // B (0..15) | C (16..31)
    const size_t rbase = (size_t)b * L_SZ + c * CH;
    for (int idx = threadIdx.x; idx < CH * 32; idx += 64) {
        int tt = idx >> 5, j = idx & 31;
        bc[tt][j] = xdbl[(rbase + tt) * 96 + 64 + j];
    }
    __syncthreads();
    float h[N_SZ];
    const size_t hbase = (size_t)c * PS_SLICE + ((size_t)b * DI_SZ + d) * N_SZ;
    #pragma unroll
    for (int q = 0; q < 4; ++q) *(float4*)&h[q * 4] = *(const float4*)&H0[hbase + q * 4];
    float dtv = dt[rbase * DI_SZ + d];
    float uv  = u[rbase * DI_SZ + d];
    float zv  = xz[rbase * (2 * DI_SZ) + DI_SZ + d];
    for (int ti = 0; ti < CH; ++ti) {
        float dtn = 0.0f, un = 0.0f, zn = 0.0f;
        if (ti + 1 < CH) {
            const size_t rn = rbase + ti + 1;
            dtn = dt[rn * DI_SZ + d];
            un  = u[rn * DI_SZ + d];
            zn  = xz[rn * (2 * DI_SZ) + DI_SZ + d];
        }
        const float dtu = dtv * uv;
        float bv[32];
        #pragma unroll
        for (int q = 0; q < 8; ++q) *(float4*)&bv[q * 4] = *(const float4*)&bc[ti][q * 4];
        float yv = 0.0f;
        #pragma unroll
        for (int n = 0; n < N_SZ; ++n) {
            float dA = __expf(dtv * A[n]);
            h[n] = dA * h[n] + dtu * bv[n];
            yv += h[n] * bv[16 + n];
        }
        const float sz = zv / (1.0f + __expf(-zv));
        y[(rbase + ti) * DI_SZ + d] = f2bf((yv + uv * Dd) * sz);
        dtv = dtn; uv = un; zv = zn;
    }
}

// ---------------------------------------------------------------- launcher ---
extern "C" void kernel_launch(void* const* d_in, const int* in_sizes, int n_in,
                              void* d_out, int out_size, void* d_ws, size_t ws_size,
                              hipStream_t stream) {
    const float* x         = (const float*)d_in[0];
    // d_in[1] hormone_vectors: unused by reference
    const float* norm_w    = (const float*)d_in[2];
    const float* in_proj_w = (const float*)d_in[3];
    const float* conv_w    = (const float*)d_in[4];
    const float* conv_b    = (const float*)d_in[5];
    const float* x_proj_w  = (const float*)d_in[6];
    const float* dt_proj_w = (const float*)d_in[7];
    const float* dt_proj_b = (const float*)d_in[8];
    const float* A_log     = (const float*)d_in[9];
    const float* Dw        = (const float*)d_in[10];
    const float* out_proj_w= (const float*)d_in[11];
    float* out = (float*)d_out;

    char* ws = (char*)d_ws;
    size_t off = 0;
    // h (bf16 [4096][1024]) aliases y (bf16 [4096][2048]); h dead before scan.
    u16* y      = (u16*)(ws + off);    off += (size_t)ROWS * DI_SZ * 2;       // 16.8 MB
    u16* h      = y;
    float* xz   = (float*)(ws + off);  off += (size_t)ROWS * 2 * DI_SZ * 4;   // 67.1 MB
    float* u    = (float*)(ws + off);  off += (size_t)ROWS * DI_SZ * 4;       // 33.5 MB
    float* xdbl = (float*)(ws + off);  off += (size_t)ROWS * 96 * 4;          // 1.6 MB
    float* dt   = (float*)(ws + off);  off += (size_t)ROWS * DI_SZ * 4;       // 33.5 MB
    float* P    = (float*)(ws + off);  off += (size_t)NCH * PS_SLICE * 4;     // 16.8 MB
    float* S    = (float*)(ws + off);  off += (size_t)NCH * PS_SLICE * 4;     // 16.8 MB
    u16* ipw_t  = (u16*)(ws + off);    off += (size_t)(2 * DI_SZ) * DM_SZ * 2;// 16.8 MB
    u16* opw_t  = (u16*)(ws + off);    off += (size_t)DM_SZ * DI_SZ * 2;      // 4.2 MB
    (void)ws_size; (void)out_size; (void)n_in; (void)in_sizes;

    // 1. rmsnorm -> h (bf16)
    rmsnorm_kernel<<<ROWS, 256, 0, stream>>>(x, norm_w, h);
    // 1b. weight converts (bf16, transposed to [N][K])
    transpose_bf16_kernel<<<dim3(2 * DI_SZ / 32, DM_SZ / 32), 256, 0, stream>>>(
        in_proj_w, ipw_t, DM_SZ, 2 * DI_SZ);
    transpose_bf16_kernel<<<dim3(DM_SZ / 32, DI_SZ / 32), 256, 0, stream>>>(
        out_proj_w, opw_t, DI_SZ, DM_SZ);
    // 2. xz = h @ in_proj_w   (4096 x 4096 x 1024, bf16 MFMA)
    mfma_gemm_bt<false><<<dim3(2 * DI_SZ / 128, ROWS / 128), 256, 0, stream>>>(
        h, ipw_t, xz, nullptr, ROWS, 2 * DI_SZ, DM_SZ);
    // 3. u = silu(conv(xz[:, :DI]))
    conv_silu_kernel<<<(ROWS * DI_SZ) / 256, 256, 0, stream>>>(xz, conv_w, conv_b, u);
    // 4. xdbl = u @ x_proj_w  (4096 x 96 x 2048)
    xproj_kernel<<<ROWS / 16, 128, 0, stream>>>(u, x_proj_w, xdbl);
    // 5. dt = softplus(xdbl[:, :64] @ dt_proj_w + b)
    dtproj_kernel<<<dim3(DI_SZ / 256, ROWS / 8), 256, 0, stream>>>(xdbl, dt_proj_w, dt_proj_b, dt);
    // 6. chunked selective scan -> y (bf16)
    scan_pass1<<<B_SZ * 32 * NCH, 64, 0, stream>>>(dt, u, xdbl, A_log, P, S);
    scan_pass2<<<PS_SLICE / 256, 256, 0, stream>>>(P, S);
    scan_pass3<<<B_SZ * 32 * NCH, 64, 0, stream>>>(dt, u, xz, xdbl, A_log, Dw, S, y);
    // 7. out = x + y @ out_proj_w  (4096 x 1024 x 2048, bf16 MFMA)
    mfma_gemm_bt<true><<<dim3(DM_SZ / 128, ROWS / 128), 256, 0, stream>>>(
        y, opw_t, out, x, ROWS, DM_SZ, DI_SZ);
}

// Round 5
// 391.287 us; speedup vs baseline: 6.1929x; 1.7832x over previous
//
#include <hip/hip_runtime.h>
#include <stddef.h>

// Problem constants (SSMLayer): B=2, L=2048, DM=1024, DI=2048, N=16, K=4, R=64
#define B_SZ 2
#define L_SZ 2048
#define DM_SZ 1024
#define DI_SZ 2048
#define N_SZ 16
#define K_SZ 4
#define R_SZ 64
#define ROWS (B_SZ * L_SZ)          // 4096
#define CH 32                       // scan chunk length
#define NCH (L_SZ / CH)             // 64 chunks
#define PS_SLICE (B_SZ * DI_SZ * N_SZ)   // 65536 floats per chunk slice

typedef unsigned short u16;
typedef unsigned int u32;
typedef short bf16x8 __attribute__((ext_vector_type(8)));
typedef float f32x4 __attribute__((ext_vector_type(4)));

__device__ __forceinline__ u16 f2bf(float f) {
    union { float f; u32 i; } v; v.f = f;
    u32 x = v.i;
    return (u16)((x + 0x7FFFu + ((x >> 16) & 1u)) >> 16);   // RNE
}
__device__ __forceinline__ float bf2f(u16 u) {
    union { u32 i; float f; } v; v.i = ((u32)u) << 16; return v.f;
}

__device__ __forceinline__ void gload_lds16(const void* g, void* l) {
    __builtin_amdgcn_global_load_lds((const __attribute__((address_space(1))) u32*)g,
                                     (__attribute__((address_space(3))) u32*)l, 16, 0, 0);
}

// ---------------------------------------------------------------- rmsnorm ----
__global__ __launch_bounds__(256) void rmsnorm_kernel(const float* __restrict__ x,
                                                      const float* __restrict__ w,
                                                      u16* __restrict__ h) {
    const int row = blockIdx.x;
    const float* xr = x + (size_t)row * DM_SZ;
    const int t4 = threadIdx.x * 4;
    float4 xv = *(const float4*)(xr + t4);
    float ss = xv.x * xv.x + xv.y * xv.y + xv.z * xv.z + xv.w * xv.w;
    #pragma unroll
    for (int off = 32; off; off >>= 1) ss += __shfl_down(ss, off);
    __shared__ float red[4];
    if ((threadIdx.x & 63) == 0) red[threadIdx.x >> 6] = ss;
    __syncthreads();
    float tot = red[0] + red[1] + red[2] + red[3];
    float rs = rsqrtf(tot * (1.0f / DM_SZ) + 1e-5f);
    float4 wv = *(const float4*)(w + t4);
    ushort4 o;
    o.x = f2bf(xv.x * rs * wv.x);
    o.y = f2bf(xv.y * rs * wv.y);
    o.z = f2bf(xv.z * rs * wv.z);
    o.w = f2bf(xv.w * rs * wv.w);
    *(ushort4*)(h + (size_t)row * DM_SZ + t4) = o;
}

// ---------------------------------------------- transpose + fp32->bf16 ------
// Wt[n][k] = bf16(W[k][n]); K, N multiples of 32. grid (N/32, K/32), 256 thr.
__global__ __launch_bounds__(256) void transpose_bf16_kernel(const float* __restrict__ W,
                                                             u16* __restrict__ Wt,
                                                             int K, int N) {
    __shared__ float t[32][33];
    const int n0 = blockIdx.x * 32, k0 = blockIdx.y * 32;
    const int tx = threadIdx.x & 31, ty = threadIdx.x >> 5;   // ty in [0,8)
    #pragma unroll
    for (int p = 0; p < 4; ++p)
        t[ty + p * 8][tx] = W[(size_t)(k0 + ty + p * 8) * N + n0 + tx];
    __syncthreads();
    #pragma unroll
    for (int p = 0; p < 4; ++p)
        Wt[(size_t)(n0 + ty + p * 8) * K + k0 + tx] = f2bf(t[tx][ty + p * 8]);
}

// ---------------------------------------------------------------- mfma gemm --
// C[M,N] = A[M,K] @ Bt[N,K]^T (+resid), A/Bt bf16 row-major, C fp32.
// 128x128 tile, BK=32, 256 threads = 4 waves, wave = 4x4 grid of 16x16x32 MFMA.
template <bool HAS_RESID>
__global__ __launch_bounds__(256, 2) void mfma_gemm_bt(const u16* __restrict__ A,
                                                       const u16* __restrict__ Bt,
                                                       float* __restrict__ C,
                                                       const float* __restrict__ resid,
                                                       int M, int N, int Kd) {
    __shared__ __align__(16) u16 As[128 * 32];   // [m][k], 8 KB
    __shared__ __align__(16) u16 Bs[128 * 32];   // [n][k], 8 KB
    const int tid = threadIdx.x;
    const int lane = tid & 63;
    const int w = tid >> 6;
    const int wm = w >> 1, wn = w & 1;
    const int bm = blockIdx.y * 128, bn = blockIdx.x * 128;

    const int r0 = (w * 2 + 0) * 16 + (lane >> 2);
    const int r1 = (w * 2 + 1) * 16 + (lane >> 2);
    const int kc = (lane & 3) * 8;
    const u16* Aq0 = A + (size_t)(bm + r0) * Kd + kc;
    const u16* Aq1 = A + (size_t)(bm + r1) * Kd + kc;
    const u16* Bq0 = Bt + (size_t)(bn + r0) * Kd + kc;
    const u16* Bq1 = Bt + (size_t)(bn + r1) * Kd + kc;
    u16* lA0 = As + (w * 2 + 0) * 512;
    u16* lA1 = As + (w * 2 + 1) * 512;
    u16* lB0 = Bs + (w * 2 + 0) * 512;
    u16* lB1 = Bs + (w * 2 + 1) * 512;

    f32x4 acc[4][4] = {};
    const int fm = (lane & 15);          // m (resp. n) within 16-tile
    const int q8 = (lane >> 4) * 8;      // k offset of this lane's 8 elems

    for (int k0 = 0; k0 < Kd; k0 += 32) {
        gload_lds16(Aq0 + k0, lA0);
        gload_lds16(Aq1 + k0, lA1);
        gload_lds16(Bq0 + k0, lB0);
        gload_lds16(Bq1 + k0, lB1);
        __syncthreads();
        bf16x8 af[4], bf[4];
        #pragma unroll
        for (int i = 0; i < 4; ++i)
            af[i] = *(const bf16x8*)&As[(wm * 64 + i * 16 + fm) * 32 + q8];
        #pragma unroll
        for (int j = 0; j < 4; ++j)
            bf[j] = *(const bf16x8*)&Bs[(wn * 64 + j * 16 + fm) * 32 + q8];
        #pragma unroll
        for (int i = 0; i < 4; ++i)
            #pragma unroll
            for (int j = 0; j < 4; ++j)
                acc[i][j] = __builtin_amdgcn_mfma_f32_16x16x32_bf16(af[i], bf[j], acc[i][j], 0, 0, 0);
        __syncthreads();
    }

    const int crow0 = bm + wm * 64 + (lane >> 4) * 4;
    const int ccol0 = bn + wn * 64 + (lane & 15);
    #pragma unroll
    for (int i = 0; i < 4; ++i) {
        #pragma unroll
        for (int r = 0; r < 4; ++r) {
            const int row = crow0 + i * 16 + r;
            #pragma unroll
            for (int j = 0; j < 4; ++j) {
                const int col = ccol0 + j * 16;
                float v = acc[i][j][r];
                if (HAS_RESID) v += resid[(size_t)row * N + col];
                C[(size_t)row * N + col] = v;
            }
        }
    }
}

// -------------------------------------------------------------- conv+silu ---
// u (bf16) = silu(depthwise-causal-conv(xz[:, :DI]))
__global__ __launch_bounds__(256) void conv_silu_kernel(const float* __restrict__ xz,
                                                        const float* __restrict__ cw,
                                                        const float* __restrict__ cb,
                                                        u16* __restrict__ u) {
    const int idx = blockIdx.x * 256 + threadIdx.x;   // over ROWS*DI
    const int d = idx & (DI_SZ - 1);
    const int r = idx >> 11;         // b*L + t
    const int t = r & (L_SZ - 1);
    float4 w4 = *(const float4*)(cw + (d << 2));
    const float w[4] = {w4.x, w4.y, w4.z, w4.w};
    float acc = cb[d];
    const float* base = xz + (size_t)r * (2 * DI_SZ) + d;
    #pragma unroll
    for (int k = 0; k < 4; ++k) {
        int tt = t - 3 + k;
        if (tt >= 0) acc += base[(ptrdiff_t)(k - 3) * (2 * DI_SZ)] * w[k];
    }
    u[idx] = f2bf(acc / (1.0f + __expf(-acc)));
}

// ------------------------------------------------------------------ x_proj ---
// xdbl[4096][96] += u[4096][2048] @ Wt_x[96][2048]^T ; split-K=8, MFMA,
// fragments straight from global (Wt_x is 384 KB -> L2-resident).
__global__ __launch_bounds__(256) void xproj_mfma(const u16* __restrict__ ubf,
                                                  const u16* __restrict__ Wt,
                                                  float* __restrict__ xdbl) {
    const int lane = threadIdx.x & 63;
    const int w = threadIdx.x >> 6;
    const int m0 = blockIdx.x * 64 + w * 16;     // 64 blocks in M
    const int k0 = blockIdx.y * 256;             // 8 K-splits
    const int fr = lane & 15;
    const int q8 = (lane >> 4) * 8;
    const u16* Arow = ubf + (size_t)(m0 + fr) * DI_SZ + k0 + q8;
    const u16* Brow = Wt + (size_t)fr * DI_SZ + k0 + q8;
    f32x4 acc[6] = {};
    #pragma unroll 2
    for (int kk = 0; kk < 256; kk += 32) {
        bf16x8 a = *(const bf16x8*)(Arow + kk);
        #pragma unroll
        for (int j = 0; j < 6; ++j) {
            bf16x8 b = *(const bf16x8*)(Brow + (size_t)(j * 16) * DI_SZ + kk);
            acc[j] = __builtin_amdgcn_mfma_f32_16x16x32_bf16(a, b, acc[j], 0, 0, 0);
        }
    }
    const int row0 = m0 + (lane >> 4) * 4;
    const int col = lane & 15;
    #pragma unroll
    for (int j = 0; j < 6; ++j)
        #pragma unroll
        for (int r = 0; r < 4; ++r)
            atomicAdd(&xdbl[(size_t)(row0 + r) * 96 + j * 16 + col], acc[j][r]);
}

// ------------------------------------------------------------ dt_proj+softplus
__global__ __launch_bounds__(256) void dtproj_kernel(const float* __restrict__ xdbl,
                                                     const float* __restrict__ W,
                                                     const float* __restrict__ bias,
                                                     float* __restrict__ dt) {
    const int col = blockIdx.x * 256 + threadIdx.x;   // d
    const int row0 = blockIdx.y * 8;
    __shared__ float dr[8][64];
    for (int idx = threadIdx.x; idx < 512; idx += 256) {
        int r = idx >> 6, k = idx & 63;
        dr[r][k] = xdbl[(size_t)(row0 + r) * 96 + k];
    }
    __syncthreads();
    float acc[8] = {};
    #pragma unroll 8
    for (int k = 0; k < 64; ++k) {
        float wv = W[(size_t)k * DI_SZ + col];
        #pragma unroll
        for (int r = 0; r < 8; ++r) acc[r] += dr[r][k] * wv;
    }
    const float b = bias[col];
    #pragma unroll
    for (int r = 0; r < 8; ++r) {
        float v = acc[r] + b;
        float sp = (v > 20.0f) ? v : log1pf(__expf(v));
        dt[(size_t)(row0 + r) * DI_SZ + col] = sp;
    }
}

// ------------------------------------------------- scan pass 1: local chunks -
__global__ __launch_bounds__(64) void scan_pass1(const float* __restrict__ dt,
                                                 const u16* __restrict__ u,
                                                 const float* __restrict__ xdbl,
                                                 const float* __restrict__ A_log,
                                                 float* __restrict__ P,
                                                 float* __restrict__ S) {
    const int c     = blockIdx.x & (NCH - 1);
    const int dtile = (blockIdx.x >> 6) & 31;
    const int b     = blockIdx.x >> 11;
    const int d     = dtile * 64 + threadIdx.x;
    float A[N_SZ];
    #pragma unroll
    for (int n = 0; n < N_SZ; ++n) A[n] = -expf(A_log[d * N_SZ + n]);
    __shared__ __align__(16) float bs[CH][16];
    const size_t rbase = (size_t)b * L_SZ + c * CH;
    for (int idx = threadIdx.x; idx < CH * 16; idx += 64) {
        int tt = idx >> 4, j = idx & 15;
        bs[tt][j] = xdbl[(rbase + tt) * 96 + 64 + j];
    }
    __syncthreads();
    float h[N_SZ] = {};
    float p[N_SZ];
    #pragma unroll
    for (int n = 0; n < N_SZ; ++n) p[n] = 1.0f;
    float dtv = dt[rbase * DI_SZ + d];
    float uv  = bf2f(u[rbase * DI_SZ + d]);
    for (int ti = 0; ti < CH; ++ti) {
        float dtn = 0.0f, un = 0.0f;
        if (ti + 1 < CH) {
            dtn = dt[(rbase + ti + 1) * DI_SZ + d];
            un  = bf2f(u[(rbase + ti + 1) * DI_SZ + d]);
        }
        const float dtu = dtv * uv;
        float bv[N_SZ];
        #pragma unroll
        for (int q = 0; q < 4; ++q) *(float4*)&bv[q * 4] = *(const float4*)&bs[ti][q * 4];
        #pragma unroll
        for (int n = 0; n < N_SZ; ++n) {
            float dA = __expf(dtv * A[n]);
            p[n] *= dA;
            h[n] = dA * h[n] + dtu * bv[n];
        }
        dtv = dtn; uv = un;
    }
    const size_t base = (size_t)c * PS_SLICE + ((size_t)b * DI_SZ + d) * N_SZ;
    #pragma unroll
    for (int q = 0; q < 4; ++q) {
        *(float4*)&P[base + q * 4] = make_float4(p[q*4], p[q*4+1], p[q*4+2], p[q*4+3]);
        *(float4*)&S[base + q * 4] = make_float4(h[q*4], h[q*4+1], h[q*4+2], h[q*4+3]);
    }
}

// --------------------------------------- scan pass 2: scan over chunks ------
__global__ __launch_bounds__(256) void scan_pass2(float* __restrict__ P,
                                                  float* __restrict__ S) {
    const int i = blockIdx.x * 256 + threadIdx.x;   // [0, PS_SLICE)
    float h = 0.0f;
    for (int c = 0; c < NCH; ++c) {
        const size_t idx = (size_t)c * PS_SLICE + i;
        const float p = P[idx];
        const float s = S[idx];
        S[idx] = h;
        h = p * h + s;
    }
}

// ----------------------------------- scan pass 3: replay with correct h0 ----
__global__ __launch_bounds__(64) void scan_pass3(const float* __restrict__ dt,
                                                 const u16* __restrict__ u,
                                                 const float* __restrict__ xz,
                                                 const float* __restrict__ xdbl,
                                                 const float* __restrict__ A_log,
                                                 const float* __restrict__ Dw,
                                                 const float* __restrict__ H0,
                                                 u16* __restrict__ y) {
    const int c     = blockIdx.x & (NCH - 1);
    const int dtile = (blockIdx.x >> 6) & 31;
    const int b     = blockIdx.x >> 11;
    const int d     = dtile * 64 + threadIdx.x;
    float A[N_SZ];
    #pragma unroll
    for (int n = 0; n < N_SZ; ++n) A[n] = -expf(A_log[d * N_SZ + n]);
    const float Dd = Dw[d];
    __shared__ __align__(16) float bc[CH][32];   // B (0..15) | C (16..31)
    const size_t rbase = (size_t)b * L_SZ + c * CH;
    for (int idx = threadIdx.x; idx < CH * 32; idx += 64) {
        int tt = idx >> 5, j = idx & 31;
        bc[tt][j] = xdbl[(rbase + tt) * 96 + 64 + j];
    }
    __syncthreads();
    float h[N_SZ];
    const size_t hbase = (size_t)c * PS_SLICE + ((size_t)b * DI_SZ + d) * N_SZ;
    #pragma unroll
    for (int q = 0; q < 4; ++q) *(float4*)&h[q * 4] = *(const float4*)&H0[hbase + q * 4];
    float dtv = dt[rbase * DI_SZ + d];
    float uv  = bf2f(u[rbase * DI_SZ + d]);
    float zv  = xz[rbase * (2 * DI_SZ) + DI_SZ + d];
    for (int ti = 0; ti < CH; ++ti) {
        float dtn = 0.0f, un = 0.0f, zn = 0.0f;
        if (ti + 1 < CH) {
            const size_t rn = rbase + ti + 1;
            dtn = dt[rn * DI_SZ + d];
            un  = bf2f(u[rn * DI_SZ + d]);
            zn  = xz[rn * (2 * DI_SZ) + DI_SZ + d];
        }
        const float dtu = dtv * uv;
        float bv[32];
        #pragma unroll
        for (int q = 0; q < 8; ++q) *(float4*)&bv[q * 4] = *(const float4*)&bc[ti][q * 4];
        float yv = 0.0f;
        #pragma unroll
        for (int n = 0; n < N_SZ; ++n) {
            float dA = __expf(dtv * A[n]);
            h[n] = dA * h[n] + dtu * bv[n];
            yv += h[n] * bv[16 + n];
        }
        const float sz = zv / (1.0f + __expf(-zv));
        y[(rbase + ti) * DI_SZ + d] = f2bf((yv + uv * Dd) * sz);
        dtv = dtn; uv = un; zv = zn;
    }
}

// ---------------------------------------------------------------- launcher ---
extern "C" void kernel_launch(void* const* d_in, const int* in_sizes, int n_in,
                              void* d_out, int out_size, void* d_ws, size_t ws_size,
                              hipStream_t stream) {
    const float* x         = (const float*)d_in[0];
    // d_in[1] hormone_vectors: unused by reference
    const float* norm_w    = (const float*)d_in[2];
    const float* in_proj_w = (const float*)d_in[3];
    const float* conv_w    = (const float*)d_in[4];
    const float* conv_b    = (const float*)d_in[5];
    const float* x_proj_w  = (const float*)d_in[6];
    const float* dt_proj_w = (const float*)d_in[7];
    const float* dt_proj_b = (const float*)d_in[8];
    const float* A_log     = (const float*)d_in[9];
    const float* Dw        = (const float*)d_in[10];
    const float* out_proj_w= (const float*)d_in[11];
    float* out = (float*)d_out;

    char* ws = (char*)d_ws;
    size_t off = 0;
    // h (bf16 [4096][1024]) aliases y (bf16 [4096][2048]); h dead before scan.
    u16* y      = (u16*)(ws + off);    off += (size_t)ROWS * DI_SZ * 2;       // 16.8 MB
    u16* h      = y;
    float* xz   = (float*)(ws + off);  off += (size_t)ROWS * 2 * DI_SZ * 4;   // 67.1 MB
    u16* u      = (u16*)(ws + off);    off += (size_t)ROWS * DI_SZ * 2;       // 16.8 MB
    float* xdbl = (float*)(ws + off);  off += (size_t)ROWS * 96 * 4;          // 1.6 MB
    float* dt   = (float*)(ws + off);  off += (size_t)ROWS * DI_SZ * 4;       // 33.5 MB
    float* P    = (float*)(ws + off);  off += (size_t)NCH * PS_SLICE * 4;     // 16.8 MB
    float* S    = (float*)(ws + off);  off += (size_t)NCH * PS_SLICE * 4;     // 16.8 MB
    u16* ipw_t  = (u16*)(ws + off);    off += (size_t)(2 * DI_SZ) * DM_SZ * 2;// 16.8 MB
    u16* opw_t  = (u16*)(ws + off);    off += (size_t)DM_SZ * DI_SZ * 2;      // 4.2 MB
    u16* xpw_t  = (u16*)(ws + off);    off += (size_t)96 * DI_SZ * 2;         // 0.4 MB
    (void)ws_size; (void)out_size; (void)n_in; (void)in_sizes;

    // 1. rmsnorm -> h (bf16)
    rmsnorm_kernel<<<ROWS, 256, 0, stream>>>(x, norm_w, h);
    // 1b. weight converts (bf16, transposed to [N][K])
    transpose_bf16_kernel<<<dim3(2 * DI_SZ / 32, DM_SZ / 32), 256, 0, stream>>>(
        in_proj_w, ipw_t, DM_SZ, 2 * DI_SZ);
    transpose_bf16_kernel<<<dim3(DM_SZ / 32, DI_SZ / 32), 256, 0, stream>>>(
        out_proj_w, opw_t, DI_SZ, DM_SZ);
    transpose_bf16_kernel<<<dim3(96 / 32, DI_SZ / 32), 256, 0, stream>>>(
        x_proj_w, xpw_t, DI_SZ, 96);
    // 2. xz = h @ in_proj_w   (4096 x 4096 x 1024, bf16 MFMA)
    mfma_gemm_bt<false><<<dim3(2 * DI_SZ / 128, ROWS / 128), 256, 0, stream>>>(
        h, ipw_t, xz, nullptr, ROWS, 2 * DI_SZ, DM_SZ);
    // 3. u = silu(conv(xz[:, :DI])) -> bf16
    conv_silu_kernel<<<(ROWS * DI_SZ) / 256, 256, 0, stream>>>(xz, conv_w, conv_b, u);
    // 4. xdbl = u @ x_proj_w  (4096 x 96 x 2048, MFMA split-K + atomics)
    hipMemsetAsync(xdbl, 0, (size_t)ROWS * 96 * 4, stream);
    xproj_mfma<<<dim3(ROWS / 64, 8), 256, 0, stream>>>(u, xpw_t, xdbl);
    // 5. dt = softplus(xdbl[:, :64] @ dt_proj_w + b)
    dtproj_kernel<<<dim3(DI_SZ / 256, ROWS / 8), 256, 0, stream>>>(xdbl, dt_proj_w, dt_proj_b, dt);
    // 6. chunked selective scan -> y (bf16)
    scan_pass1<<<B_SZ * 32 * NCH, 64, 0, stream>>>(dt, u, xdbl, A_log, P, S);
    scan_pass2<<<PS_SLICE / 256, 256, 0, stream>>>(P, S);
    scan_pass3<<<B_SZ * 32 * NCH, 64, 0, stream>>>(dt, u, xz, xdbl, A_log, Dw, S, y);
    // 7. out = x + y @ out_proj_w  (4096 x 1024 x 2048, bf16 MFMA)
    mfma_gemm_bt<true><<<dim3(DM_SZ / 128, ROWS / 128), 256, 0, stream>>>(
        y, opw_t, out, x, ROWS, DM_SZ, DI_SZ);
}

// Round 6
// 375.098 us; speedup vs baseline: 6.4602x; 1.0432x over previous
//
#include <hip/hip_runtime.h>
#include <stddef.h>

// Problem constants (SSMLayer): B=2, L=2048, DM=1024, DI=2048, N=16, K=4, R=64
#define B_SZ 2
#define L_SZ 2048
#define DM_SZ 1024
#define DI_SZ 2048
#define N_SZ 16
#define K_SZ 4
#define R_SZ 64
#define ROWS (B_SZ * L_SZ)          // 4096
#define CH 32                       // scan chunk length
#define NCH (L_SZ / CH)             // 64 chunks
#define PS_SLICE (B_SZ * DI_SZ * N_SZ)   // 65536 floats per chunk slice

typedef unsigned short u16;
typedef unsigned int u32;
typedef short bf16x8 __attribute__((ext_vector_type(8)));
typedef float f32x4 __attribute__((ext_vector_type(4)));

__device__ __forceinline__ u16 f2bf(float f) {
    union { float f; u32 i; } v; v.f = f;
    u32 x = v.i;
    return (u16)((x + 0x7FFFu + ((x >> 16) & 1u)) >> 16);   // RNE
}
__device__ __forceinline__ float bf2f(u16 u) {
    union { u32 i; float f; } v; v.i = ((u32)u) << 16; return v.f;
}

__device__ __forceinline__ void gload_lds16(const void* g, void* l) {
    __builtin_amdgcn_global_load_lds((const __attribute__((address_space(1))) u32*)g,
                                     (__attribute__((address_space(3))) u32*)l, 16, 0, 0);
}

// ---------------------------------------------------------------- rmsnorm ----
__global__ __launch_bounds__(256) void rmsnorm_kernel(const float* __restrict__ x,
                                                      const float* __restrict__ w,
                                                      u16* __restrict__ h) {
    const int row = blockIdx.x;
    const float* xr = x + (size_t)row * DM_SZ;
    const int t4 = threadIdx.x * 4;
    float4 xv = *(const float4*)(xr + t4);
    float ss = xv.x * xv.x + xv.y * xv.y + xv.z * xv.z + xv.w * xv.w;
    #pragma unroll
    for (int off = 32; off; off >>= 1) ss += __shfl_down(ss, off);
    __shared__ float red[4];
    if ((threadIdx.x & 63) == 0) red[threadIdx.x >> 6] = ss;
    __syncthreads();
    float tot = red[0] + red[1] + red[2] + red[3];
    float rs = rsqrtf(tot * (1.0f / DM_SZ) + 1e-5f);
    float4 wv = *(const float4*)(w + t4);
    ushort4 o;
    o.x = f2bf(xv.x * rs * wv.x);
    o.y = f2bf(xv.y * rs * wv.y);
    o.z = f2bf(xv.z * rs * wv.z);
    o.w = f2bf(xv.w * rs * wv.w);
    *(ushort4*)(h + (size_t)row * DM_SZ + t4) = o;
}

// ---------------------------------------------- transpose + fp32->bf16 ------
// Wt[n][k] = bf16(W[k][n]); K, N multiples of 32. grid (N/32, K/32), 256 thr.
__global__ __launch_bounds__(256) void transpose_bf16_kernel(const float* __restrict__ W,
                                                             u16* __restrict__ Wt,
                                                             int K, int N) {
    __shared__ float t[32][33];
    const int n0 = blockIdx.x * 32, k0 = blockIdx.y * 32;
    const int tx = threadIdx.x & 31, ty = threadIdx.x >> 5;   // ty in [0,8)
    #pragma unroll
    for (int p = 0; p < 4; ++p)
        t[ty + p * 8][tx] = W[(size_t)(k0 + ty + p * 8) * N + n0 + tx];
    __syncthreads();
    #pragma unroll
    for (int p = 0; p < 4; ++p)
        Wt[(size_t)(n0 + ty + p * 8) * K + k0 + tx] = f2bf(t[tx][ty + p * 8]);
}

// ---------------------------------------------------------------- mfma gemm --
// C[M,N] = A[M,K] @ Bt[N,K]^T (+resid), A/Bt bf16 row-major, C fp32.
// 128x128 tile, BK=32, 256 threads = 4 waves, wave = 4x4 grid of 16x16x32 MFMA.
template <bool HAS_RESID>
__global__ __launch_bounds__(256, 2) void mfma_gemm_bt(const u16* __restrict__ A,
                                                       const u16* __restrict__ Bt,
                                                       float* __restrict__ C,
                                                       const float* __restrict__ resid,
                                                       int M, int N, int Kd) {
    __shared__ __align__(16) u16 As[128 * 32];   // [m][k], 8 KB
    __shared__ __align__(16) u16 Bs[128 * 32];   // [n][k], 8 KB
    const int tid = threadIdx.x;
    const int lane = tid & 63;
    const int w = tid >> 6;
    const int wm = w >> 1, wn = w & 1;
    const int bm = blockIdx.y * 128, bn = blockIdx.x * 128;

    const int r0 = (w * 2 + 0) * 16 + (lane >> 2);
    const int r1 = (w * 2 + 1) * 16 + (lane >> 2);
    const int kc = (lane & 3) * 8;
    const u16* Aq0 = A + (size_t)(bm + r0) * Kd + kc;
    const u16* Aq1 = A + (size_t)(bm + r1) * Kd + kc;
    const u16* Bq0 = Bt + (size_t)(bn + r0) * Kd + kc;
    const u16* Bq1 = Bt + (size_t)(bn + r1) * Kd + kc;
    u16* lA0 = As + (w * 2 + 0) * 512;
    u16* lA1 = As + (w * 2 + 1) * 512;
    u16* lB0 = Bs + (w * 2 + 0) * 512;
    u16* lB1 = Bs + (w * 2 + 1) * 512;

    f32x4 acc[4][4] = {};
    const int fm = (lane & 15);          // m (resp. n) within 16-tile
    const int q8 = (lane >> 4) * 8;      // k offset of this lane's 8 elems

    for (int k0 = 0; k0 < Kd; k0 += 32) {
        gload_lds16(Aq0 + k0, lA0);
        gload_lds16(Aq1 + k0, lA1);
        gload_lds16(Bq0 + k0, lB0);
        gload_lds16(Bq1 + k0, lB1);
        __syncthreads();
        bf16x8 af[4], bf[4];
        #pragma unroll
        for (int i = 0; i < 4; ++i)
            af[i] = *(const bf16x8*)&As[(wm * 64 + i * 16 + fm) * 32 + q8];
        #pragma unroll
        for (int j = 0; j < 4; ++j)
            bf[j] = *(const bf16x8*)&Bs[(wn * 64 + j * 16 + fm) * 32 + q8];
        #pragma unroll
        for (int i = 0; i < 4; ++i)
            #pragma unroll
            for (int j = 0; j < 4; ++j)
                acc[i][j] = __builtin_amdgcn_mfma_f32_16x16x32_bf16(af[i], bf[j], acc[i][j], 0, 0, 0);
        __syncthreads();
    }

    const int crow0 = bm + wm * 64 + (lane >> 4) * 4;
    const int ccol0 = bn + wn * 64 + (lane & 15);
    #pragma unroll
    for (int i = 0; i < 4; ++i) {
        #pragma unroll
        for (int r = 0; r < 4; ++r) {
            const int row = crow0 + i * 16 + r;
            #pragma unroll
            for (int j = 0; j < 4; ++j) {
                const int col = ccol0 + j * 16;
                float v = acc[i][j][r];
                if (HAS_RESID) v += resid[(size_t)row * N + col];
                C[(size_t)row * N + col] = v;
            }
        }
    }
}

// -------------------------------------------------------------- conv+silu ---
// u (bf16) = silu(depthwise-causal-conv(xz[:, :DI]))
__global__ __launch_bounds__(256) void conv_silu_kernel(const float* __restrict__ xz,
                                                        const float* __restrict__ cw,
                                                        const float* __restrict__ cb,
                                                        u16* __restrict__ u) {
    const int idx = blockIdx.x * 256 + threadIdx.x;   // over ROWS*DI
    const int d = idx & (DI_SZ - 1);
    const int r = idx >> 11;         // b*L + t
    const int t = r & (L_SZ - 1);
    float4 w4 = *(const float4*)(cw + (d << 2));
    const float w[4] = {w4.x, w4.y, w4.z, w4.w};
    float acc = cb[d];
    const float* base = xz + (size_t)r * (2 * DI_SZ) + d;
    #pragma unroll
    for (int k = 0; k < 4; ++k) {
        int tt = t - 3 + k;
        if (tt >= 0) acc += base[(ptrdiff_t)(k - 3) * (2 * DI_SZ)] * w[k];
    }
    u[idx] = f2bf(acc / (1.0f + __expf(-acc)));
}

// ------------------------------------------------------------------ x_proj ---
// xdbl[4096][96] += u[4096][2048] @ Wt_x[96][2048]^T ; split-K=8, MFMA,
// fragments straight from global (Wt_x is 384 KB -> L2-resident).
__global__ __launch_bounds__(256) void xproj_mfma(const u16* __restrict__ ubf,
                                                  const u16* __restrict__ Wt,
                                                  float* __restrict__ xdbl) {
    const int lane = threadIdx.x & 63;
    const int w = threadIdx.x >> 6;
    const int m0 = blockIdx.x * 64 + w * 16;     // 64 blocks in M
    const int k0 = blockIdx.y * 256;             // 8 K-splits
    const int fr = lane & 15;
    const int q8 = (lane >> 4) * 8;
    const u16* Arow = ubf + (size_t)(m0 + fr) * DI_SZ + k0 + q8;
    const u16* Brow = Wt + (size_t)fr * DI_SZ + k0 + q8;
    f32x4 acc[6] = {};
    #pragma unroll 2
    for (int kk = 0; kk < 256; kk += 32) {
        bf16x8 a = *(const bf16x8*)(Arow + kk);
        #pragma unroll
        for (int j = 0; j < 6; ++j) {
            bf16x8 b = *(const bf16x8*)(Brow + (size_t)(j * 16) * DI_SZ + kk);
            acc[j] = __builtin_amdgcn_mfma_f32_16x16x32_bf16(a, b, acc[j], 0, 0, 0);
        }
    }
    const int row0 = m0 + (lane >> 4) * 4;
    const int col = lane & 15;
    #pragma unroll
    for (int j = 0; j < 6; ++j)
        #pragma unroll
        for (int r = 0; r < 4; ++r)
            atomicAdd(&xdbl[(size_t)(row0 + r) * 96 + j * 16 + col], acc[j][r]);
}

// --------------------------------------------------- xdbl dt-slice -> bf16 --
__global__ __launch_bounds__(256) void dtslice_bf16_kernel(const float* __restrict__ xdbl,
                                                           u16* __restrict__ out) {
    const int idx = blockIdx.x * 256 + threadIdx.x;   // over ROWS*64
    const int r = idx >> 6, k = idx & 63;
    out[idx] = f2bf(xdbl[(size_t)r * 96 + k]);
}

// -------------------------------------------------- dt_proj (MFMA) ----------
// dt[4096][2048] = bf16(softplus(Axd[4096][64] @ Wt[2048][64]^T + bias)).
// 128x128 tile, K=64 (two BK=32 steps), 4 waves.
__global__ __launch_bounds__(256, 2) void dtproj_mfma(const u16* __restrict__ Axd,
                                                      const u16* __restrict__ Wt,
                                                      const float* __restrict__ bias,
                                                      u16* __restrict__ dt) {
    __shared__ __align__(16) u16 As[128 * 64];   // 16 KB
    __shared__ __align__(16) u16 Bs[128 * 64];   // 16 KB
    const int tid = threadIdx.x;
    const int lane = tid & 63;
    const int w = tid >> 6;
    const int wm = w >> 1, wn = w & 1;
    const int bm = blockIdx.y * 128, bn = blockIdx.x * 128;

    // staging: full K=64 row = 128 B = 8 chunks of 16 B. lane L -> row L>>3,
    // chunk L&7. Wave instr q in {0..3} covers rows (w*4+q)*8 .. +7.
    #pragma unroll
    for (int q = 0; q < 4; ++q) {
        const int rr = (w * 4 + q) * 8 + (lane >> 3);
        const int kc = (lane & 7) * 8;
        gload_lds16(Axd + (size_t)(bm + rr) * 64 + kc, As + (w * 4 + q) * 512);
        gload_lds16(Wt  + (size_t)(bn + rr) * 64 + kc, Bs + (w * 4 + q) * 512);
    }
    __syncthreads();

    const int fm = lane & 15;
    const int q8 = (lane >> 4) * 8;
    f32x4 acc[4][4] = {};
    #pragma unroll
    for (int k0 = 0; k0 < 64; k0 += 32) {
        bf16x8 af[4], bf[4];
        #pragma unroll
        for (int i = 0; i < 4; ++i)
            af[i] = *(const bf16x8*)&As[(wm * 64 + i * 16 + fm) * 64 + k0 + q8];
        #pragma unroll
        for (int j = 0; j < 4; ++j)
            bf[j] = *(const bf16x8*)&Bs[(wn * 64 + j * 16 + fm) * 64 + k0 + q8];
        #pragma unroll
        for (int i = 0; i < 4; ++i)
            #pragma unroll
            for (int j = 0; j < 4; ++j)
                acc[i][j] = __builtin_amdgcn_mfma_f32_16x16x32_bf16(af[i], bf[j], acc[i][j], 0, 0, 0);
    }

    const int crow0 = bm + wm * 64 + (lane >> 4) * 4;
    const int ccol0 = bn + wn * 64 + (lane & 15);
    #pragma unroll
    for (int j = 0; j < 4; ++j) {
        const int col = ccol0 + j * 16;
        const float b = bias[col];
        #pragma unroll
        for (int i = 0; i < 4; ++i) {
            #pragma unroll
            for (int r = 0; r < 4; ++r) {
                const int row = crow0 + i * 16 + r;
                float v = acc[i][j][r] + b;
                float sp = (v > 20.0f) ? v : log1pf(__expf(v));
                dt[(size_t)row * DI_SZ + col] = f2bf(sp);
            }
        }
    }
}

// ------------------------------------------------- scan pass 1: local chunks -
__global__ __launch_bounds__(64) void scan_pass1(const u16* __restrict__ dt,
                                                 const u16* __restrict__ u,
                                                 const float* __restrict__ xdbl,
                                                 const float* __restrict__ A_log,
                                                 float* __restrict__ P,
                                                 float* __restrict__ S) {
    const int c     = blockIdx.x & (NCH - 1);
    const int dtile = (blockIdx.x >> 6) & 31;
    const int b     = blockIdx.x >> 11;
    const int d     = dtile * 64 + threadIdx.x;
    float A[N_SZ];
    #pragma unroll
    for (int n = 0; n < N_SZ; ++n) A[n] = -expf(A_log[d * N_SZ + n]);
    __shared__ __align__(16) float bs[CH][16];
    const size_t rbase = (size_t)b * L_SZ + c * CH;
    for (int idx = threadIdx.x; idx < CH * 16; idx += 64) {
        int tt = idx >> 4, j = idx & 15;
        bs[tt][j] = xdbl[(rbase + tt) * 96 + 64 + j];
    }
    __syncthreads();
    float h[N_SZ] = {};
    float p[N_SZ];
    #pragma unroll
    for (int n = 0; n < N_SZ; ++n) p[n] = 1.0f;
    float dtv = bf2f(dt[rbase * DI_SZ + d]);
    float uv  = bf2f(u[rbase * DI_SZ + d]);
    for (int ti = 0; ti < CH; ++ti) {
        float dtn = 0.0f, un = 0.0f;
        if (ti + 1 < CH) {
            dtn = bf2f(dt[(rbase + ti + 1) * DI_SZ + d]);
            un  = bf2f(u[(rbase + ti + 1) * DI_SZ + d]);
        }
        const float dtu = dtv * uv;
        float bv[N_SZ];
        #pragma unroll
        for (int q = 0; q < 4; ++q) *(float4*)&bv[q * 4] = *(const float4*)&bs[ti][q * 4];
        #pragma unroll
        for (int n = 0; n < N_SZ; ++n) {
            float dA = __expf(dtv * A[n]);
            p[n] *= dA;
            h[n] = dA * h[n] + dtu * bv[n];
        }
        dtv = dtn; uv = un;
    }
    const size_t base = (size_t)c * PS_SLICE + ((size_t)b * DI_SZ + d) * N_SZ;
    #pragma unroll
    for (int q = 0; q < 4; ++q) {
        *(float4*)&P[base + q * 4] = make_float4(p[q*4], p[q*4+1], p[q*4+2], p[q*4+3]);
        *(float4*)&S[base + q * 4] = make_float4(h[q*4], h[q*4+1], h[q*4+2], h[q*4+3]);
    }
}

// --------------------------------------- scan pass 2: scan over chunks ------
__global__ __launch_bounds__(256) void scan_pass2(float* __restrict__ P,
                                                  float* __restrict__ S) {
    const int i = blockIdx.x * 256 + threadIdx.x;   // [0, PS_SLICE)
    float h = 0.0f;
    for (int c = 0; c < NCH; ++c) {
        const size_t idx = (size_t)c * PS_SLICE + i;
        const float p = P[idx];
        const float s = S[idx];
        S[idx] = h;
        h = p * h + s;
    }
}

// ----------------------------------- scan pass 3: replay with correct h0 ----
__global__ __launch_bounds__(64) void scan_pass3(const u16* __restrict__ dt,
                                                 const u16* __restrict__ u,
                                                 const float* __restrict__ xz,
                                                 const float* __restrict__ xdbl,
                                                 const float* __restrict__ A_log,
                                                 const float* __restrict__ Dw,
                                                 const float* __restrict__ H0,
                                                 u16* __restrict__ y) {
    const int c     = blockIdx.x & (NCH - 1);
    const int dtile = (blockIdx.x >> 6) & 31;
    const int b     = blockIdx.x >> 11;
    const int d     = dtile * 64 + threadIdx.x;
    float A[N_SZ];
    #pragma unroll
    for (int n = 0; n < N_SZ; ++n) A[n] = -expf(A_log[d * N_SZ + n]);
    const float Dd = Dw[d];
    __shared__ __align__(16) float bc[CH][32];   // B (0..15) | C (16..31)
    const size_t rbase = (size_t)b * L_SZ + c * CH;
    for (int idx = threadIdx.x; idx < CH * 32; idx += 64) {
        int tt = idx >> 5, j = idx & 31;
        bc[tt][j] = xdbl[(rbase + tt) * 96 + 64 + j];
    }
    __syncthreads();
    float h[N_SZ];
    const size_t hbase = (size_t)c * PS_SLICE + ((size_t)b * DI_SZ + d) * N_SZ;
    #pragma unroll
    for (int q = 0; q < 4; ++q) *(float4*)&h[q * 4] = *(const float4*)&H0[hbase + q * 4];
    float dtv = bf2f(dt[rbase * DI_SZ + d]);
    float uv  = bf2f(u[rbase * DI_SZ + d]);
    float zv  = xz[rbase * (2 * DI_SZ) + DI_SZ + d];
    for (int ti = 0; ti < CH; ++ti) {
        float dtn = 0.0f, un = 0.0f, zn = 0.0f;
        if (ti + 1 < CH) {
            const size_t rn = rbase + ti + 1;
            dtn = bf2f(dt[rn * DI_SZ + d]);
            un  = bf2f(u[rn * DI_SZ + d]);
            zn  = xz[rn * (2 * DI_SZ) + DI_SZ + d];
        }
        const float dtu = dtv * uv;
        float bv[32];
        #pragma unroll
        for (int q = 0; q < 8; ++q) *(float4*)&bv[q * 4] = *(const float4*)&bc[ti][q * 4];
        float yv = 0.0f;
        #pragma unroll
        for (int n = 0; n < N_SZ; ++n) {
            float dA = __expf(dtv * A[n]);
            h[n] = dA * h[n] + dtu * bv[n];
            yv += h[n] * bv[16 + n];
        }
        const float sz = zv / (1.0f + __expf(-zv));
        y[(rbase + ti) * DI_SZ + d] = f2bf((yv + uv * Dd) * sz);
        dtv = dtn; uv = un; zv = zn;
    }
}

// ---------------------------------------------------------------- launcher ---
extern "C" void kernel_launch(void* const* d_in, const int* in_sizes, int n_in,
                              void* d_out, int out_size, void* d_ws, size_t ws_size,
                              hipStream_t stream) {
    const float* x         = (const float*)d_in[0];
    // d_in[1] hormone_vectors: unused by reference
    const float* norm_w    = (const float*)d_in[2];
    const float* in_proj_w = (const float*)d_in[3];
    const float* conv_w    = (const float*)d_in[4];
    const float* conv_b    = (const float*)d_in[5];
    const float* x_proj_w  = (const float*)d_in[6];
    const float* dt_proj_w = (const float*)d_in[7];
    const float* dt_proj_b = (const float*)d_in[8];
    const float* A_log     = (const float*)d_in[9];
    const float* Dw        = (const float*)d_in[10];
    const float* out_proj_w= (const float*)d_in[11];
    float* out = (float*)d_out;

    char* ws = (char*)d_ws;
    size_t off = 0;
    // h (bf16 [4096][1024]) aliases y (bf16 [4096][2048]); h dead before scan.
    u16* y      = (u16*)(ws + off);    off += (size_t)ROWS * DI_SZ * 2;       // 16.8 MB
    u16* h      = y;
    float* xz   = (float*)(ws + off);  off += (size_t)ROWS * 2 * DI_SZ * 4;   // 67.1 MB
    u16* u      = (u16*)(ws + off);    off += (size_t)ROWS * DI_SZ * 2;       // 16.8 MB
    float* xdbl = (float*)(ws + off);  off += (size_t)ROWS * 96 * 4;          // 1.6 MB
    u16* dt     = (u16*)(ws + off);    off += (size_t)ROWS * DI_SZ * 2;       // 16.8 MB
    float* P    = (float*)(ws + off);  off += (size_t)NCH * PS_SLICE * 4;     // 16.8 MB
    float* S    = (float*)(ws + off);  off += (size_t)NCH * PS_SLICE * 4;     // 16.8 MB
    u16* ipw_t  = (u16*)(ws + off);    off += (size_t)(2 * DI_SZ) * DM_SZ * 2;// 16.8 MB
    u16* opw_t  = (u16*)(ws + off);    off += (size_t)DM_SZ * DI_SZ * 2;      // 4.2 MB
    u16* xpw_t  = (u16*)(ws + off);    off += (size_t)96 * DI_SZ * 2;         // 0.4 MB
    u16* dtw_t  = (u16*)(ws + off);    off += (size_t)DI_SZ * R_SZ * 2;       // 0.26 MB
    u16* xdbl_bf= (u16*)(ws + off);    off += (size_t)ROWS * R_SZ * 2;        // 0.5 MB
    (void)ws_size; (void)out_size; (void)n_in; (void)in_sizes;

    // 1. rmsnorm -> h (bf16)
    rmsnorm_kernel<<<ROWS, 256, 0, stream>>>(x, norm_w, h);
    // 1b. weight converts (bf16, transposed to [N][K])
    transpose_bf16_kernel<<<dim3(2 * DI_SZ / 32, DM_SZ / 32), 256, 0, stream>>>(
        in_proj_w, ipw_t, DM_SZ, 2 * DI_SZ);
    transpose_bf16_kernel<<<dim3(DM_SZ / 32, DI_SZ / 32), 256, 0, stream>>>(
        out_proj_w, opw_t, DI_SZ, DM_SZ);
    transpose_bf16_kernel<<<dim3(96 / 32, DI_SZ / 32), 256, 0, stream>>>(
        x_proj_w, xpw_t, DI_SZ, 96);
    transpose_bf16_kernel<<<dim3(DI_SZ / 32, R_SZ / 32), 256, 0, stream>>>(
        dt_proj_w, dtw_t, R_SZ, DI_SZ);
    // 2. xz = h @ in_proj_w   (4096 x 4096 x 1024, bf16 MFMA)
    mfma_gemm_bt<false><<<dim3(2 * DI_SZ / 128, ROWS / 128), 256, 0, stream>>>(
        h, ipw_t, xz, nullptr, ROWS, 2 * DI_SZ, DM_SZ);
    // 3. u = silu(conv(xz[:, :DI])) -> bf16
    conv_silu_kernel<<<(ROWS * DI_SZ) / 256, 256, 0, stream>>>(xz, conv_w, conv_b, u);
    // 4. xdbl = u @ x_proj_w  (4096 x 96 x 2048, MFMA split-K + atomics)
    hipMemsetAsync(xdbl, 0, (size_t)ROWS * 96 * 4, stream);
    xproj_mfma<<<dim3(ROWS / 64, 8), 256, 0, stream>>>(u, xpw_t, xdbl);
    // 5. dt = bf16(softplus(xdbl[:, :64] @ dt_proj_w + b))  (MFMA)
    dtslice_bf16_kernel<<<(ROWS * R_SZ) / 256, 256, 0, stream>>>(xdbl, xdbl_bf);
    dtproj_mfma<<<dim3(DI_SZ / 128, ROWS / 128), 256, 0, stream>>>(
        xdbl_bf, dtw_t, dt_proj_b, dt);
    // 6. chunked selective scan -> y (bf16)
    scan_pass1<<<B_SZ * 32 * NCH, 64, 0, stream>>>(dt, u, xdbl, A_log, P, S);
    scan_pass2<<<PS_SLICE / 256, 256, 0, stream>>>(P, S);
    scan_pass3<<<B_SZ * 32 * NCH, 64, 0, stream>>>(dt, u, xz, xdbl, A_log, Dw, S, y);
    // 7. out = x + y @ out_proj_w  (4096 x 1024 x 2048, bf16 MFMA)
    mfma_gemm_bt<true><<<dim3(DM_SZ / 128, ROWS / 128), 256, 0, stream>>>(
        y, opw_t, out, x, ROWS, DM_SZ, DI_SZ);
}

// Round 7
// 364.437 us; speedup vs baseline: 6.6492x; 1.0293x over previous
//
#include <hip/hip_runtime.h>
#include <stddef.h>

// Problem constants (SSMLayer): B=2, L=2048, DM=1024, DI=2048, N=16, K=4, R=64
#define B_SZ 2
#define L_SZ 2048
#define DM_SZ 1024
#define DI_SZ 2048
#define N_SZ 16
#define K_SZ 4
#define R_SZ 64
#define ROWS (B_SZ * L_SZ)          // 4096
#define CH 64                       // scan chunk length
#define NCH (L_SZ / CH)             // 32 chunks
#define PS_SLICE (B_SZ * DI_SZ * N_SZ)   // 65536 floats per chunk slice

typedef unsigned short u16;
typedef unsigned int u32;
typedef short bf16x8 __attribute__((ext_vector_type(8)));
typedef float f32x4 __attribute__((ext_vector_type(4)));

__device__ __forceinline__ u16 f2bf(float f) {
    union { float f; u32 i; } v; v.f = f;
    u32 x = v.i;
    return (u16)((x + 0x7FFFu + ((x >> 16) & 1u)) >> 16);   // RNE
}
__device__ __forceinline__ float bf2f(u16 u) {
    union { u32 i; float f; } v; v.i = ((u32)u) << 16; return v.f;
}

__device__ __forceinline__ void gload_lds16(const void* g, void* l) {
    __builtin_amdgcn_global_load_lds((const __attribute__((address_space(1))) u32*)g,
                                     (__attribute__((address_space(3))) u32*)l, 16, 0, 0);
}

// ---------------------------------------------------------------- rmsnorm ----
__global__ __launch_bounds__(256) void rmsnorm_kernel(const float* __restrict__ x,
                                                      const float* __restrict__ w,
                                                      u16* __restrict__ h) {
    const int row = blockIdx.x;
    const float* xr = x + (size_t)row * DM_SZ;
    const int t4 = threadIdx.x * 4;
    float4 xv = *(const float4*)(xr + t4);
    float ss = xv.x * xv.x + xv.y * xv.y + xv.z * xv.z + xv.w * xv.w;
    #pragma unroll
    for (int off = 32; off; off >>= 1) ss += __shfl_down(ss, off);
    __shared__ float red[4];
    if ((threadIdx.x & 63) == 0) red[threadIdx.x >> 6] = ss;
    __syncthreads();
    float tot = red[0] + red[1] + red[2] + red[3];
    float rs = rsqrtf(tot * (1.0f / DM_SZ) + 1e-5f);
    float4 wv = *(const float4*)(w + t4);
    ushort4 o;
    o.x = f2bf(xv.x * rs * wv.x);
    o.y = f2bf(xv.y * rs * wv.y);
    o.z = f2bf(xv.z * rs * wv.z);
    o.w = f2bf(xv.w * rs * wv.w);
    *(ushort4*)(h + (size_t)row * DM_SZ + t4) = o;
}

// ---------------------------------------------- transpose + fp32->bf16 ------
// Wt[n][k] = bf16(W[k][n]) for a 32x32 tile at (bx*32, by*32).
__device__ __forceinline__ void transpose_tile(const float* __restrict__ W,
                                               u16* __restrict__ Wt,
                                               int K, int N, int bx, int by) {
    __shared__ float t[32][33];
    const int n0 = bx * 32, k0 = by * 32;
    const int tx = threadIdx.x & 31, ty = threadIdx.x >> 5;   // ty in [0,8)
    #pragma unroll
    for (int p = 0; p < 4; ++p)
        t[ty + p * 8][tx] = W[(size_t)(k0 + ty + p * 8) * N + n0 + tx];
    __syncthreads();
    #pragma unroll
    for (int p = 0; p < 4; ++p)
        Wt[(size_t)(n0 + ty + p * 8) * K + k0 + tx] = f2bf(t[tx][ty + p * 8]);
}

// All four weight transposes in one dispatch (block-range switch; uniform per block).
__global__ __launch_bounds__(256) void transpose_all(const float* __restrict__ ipw, u16* __restrict__ ipw_t,
                                                     const float* __restrict__ opw, u16* __restrict__ opw_t,
                                                     const float* __restrict__ xpw, u16* __restrict__ xpw_t,
                                                     const float* __restrict__ dtw, u16* __restrict__ dtw_t) {
    int b = blockIdx.x;
    if (b < 4096) {                 // in_proj: K=1024, N=4096 -> 128 x 32
        transpose_tile(ipw, ipw_t, DM_SZ, 2 * DI_SZ, b & 127, b >> 7);
    } else if (b < 6144) {          // out_proj: K=2048, N=1024 -> 32 x 64
        b -= 4096;
        transpose_tile(opw, opw_t, DI_SZ, DM_SZ, b & 31, b >> 5);
    } else if (b < 6336) {          // x_proj: K=2048, N=96 -> 3 x 64
        b -= 6144;
        transpose_tile(xpw, xpw_t, DI_SZ, 96, b % 3, b / 3);
    } else {                        // dt_proj: K=64, N=2048 -> 64 x 2
        b -= 6336;
        transpose_tile(dtw, dtw_t, R_SZ, DI_SZ, b & 63, b >> 6);
    }
}

// ------------------------------------------------------------ GEMM1 (xz) ----
// xz[M,N] = bf16( A[M,K] @ Bt[N,K]^T ), 128x128 tile, BK=32, 4 waves 2x2.
__global__ __launch_bounds__(256, 2) void mfma_gemm_xz(const u16* __restrict__ A,
                                                       const u16* __restrict__ Bt,
                                                       u16* __restrict__ C,
                                                       int M, int N, int Kd) {
    __shared__ __align__(16) u16 As[128 * 32];   // [m][k], 8 KB
    __shared__ __align__(16) u16 Bs[128 * 32];   // [n][k], 8 KB
    const int tid = threadIdx.x;
    const int lane = tid & 63;
    const int w = tid >> 6;
    const int wm = w >> 1, wn = w & 1;
    const int bm = blockIdx.y * 128, bn = blockIdx.x * 128;

    const int r0 = (w * 2 + 0) * 16 + (lane >> 2);
    const int r1 = (w * 2 + 1) * 16 + (lane >> 2);
    const int kc = (lane & 3) * 8;
    const u16* Aq0 = A + (size_t)(bm + r0) * Kd + kc;
    const u16* Aq1 = A + (size_t)(bm + r1) * Kd + kc;
    const u16* Bq0 = Bt + (size_t)(bn + r0) * Kd + kc;
    const u16* Bq1 = Bt + (size_t)(bn + r1) * Kd + kc;
    u16* lA0 = As + (w * 2 + 0) * 512;
    u16* lA1 = As + (w * 2 + 1) * 512;
    u16* lB0 = Bs + (w * 2 + 0) * 512;
    u16* lB1 = Bs + (w * 2 + 1) * 512;

    f32x4 acc[4][4] = {};
    const int fm = (lane & 15);
    const int q8 = (lane >> 4) * 8;

    for (int k0 = 0; k0 < Kd; k0 += 32) {
        gload_lds16(Aq0 + k0, lA0);
        gload_lds16(Aq1 + k0, lA1);
        gload_lds16(Bq0 + k0, lB0);
        gload_lds16(Bq1 + k0, lB1);
        __syncthreads();
        bf16x8 af[4], bf[4];
        #pragma unroll
        for (int i = 0; i < 4; ++i)
            af[i] = *(const bf16x8*)&As[(wm * 64 + i * 16 + fm) * 32 + q8];
        #pragma unroll
        for (int j = 0; j < 4; ++j)
            bf[j] = *(const bf16x8*)&Bs[(wn * 64 + j * 16 + fm) * 32 + q8];
        #pragma unroll
        for (int i = 0; i < 4; ++i)
            #pragma unroll
            for (int j = 0; j < 4; ++j)
                acc[i][j] = __builtin_amdgcn_mfma_f32_16x16x32_bf16(af[i], bf[j], acc[i][j], 0, 0, 0);
        __syncthreads();
    }

    const int crow0 = bm + wm * 64 + (lane >> 4) * 4;
    const int ccol0 = bn + wn * 64 + (lane & 15);
    #pragma unroll
    for (int i = 0; i < 4; ++i)
        #pragma unroll
        for (int r = 0; r < 4; ++r) {
            const int row = crow0 + i * 16 + r;
            #pragma unroll
            for (int j = 0; j < 4; ++j)
                C[(size_t)row * N + ccol0 + j * 16] = f2bf(acc[i][j][r]);
        }
}

// ------------------------------------------------------- GEMM4 (out) --------
// C[M,N] = A[M,K] @ Bt[N,K]^T + resid, fp32 C. 128x64 tile -> 2 blocks/CU.
// 4 waves 2x2; wave covers 64x32 = 4x2 mfma tiles.
__global__ __launch_bounds__(256, 2) void mfma_gemm_rn(const u16* __restrict__ A,
                                                       const u16* __restrict__ Bt,
                                                       float* __restrict__ C,
                                                       const float* __restrict__ resid,
                                                       int M, int N, int Kd) {
    __shared__ __align__(16) u16 As[128 * 32];   // 8 KB
    __shared__ __align__(16) u16 Bs[64 * 32];    // 4 KB
    const int tid = threadIdx.x;
    const int lane = tid & 63;
    const int w = tid >> 6;
    const int wm = w >> 1, wn = w & 1;
    const int bm = blockIdx.y * 128, bn = blockIdx.x * 64;

    // A staging: 8 groups of 16 rows (w*2+q); B staging: 4 groups, wave w -> group w.
    const int rA0 = (w * 2 + 0) * 16 + (lane >> 2);
    const int rA1 = (w * 2 + 1) * 16 + (lane >> 2);
    const int rB  = w * 16 + (lane >> 2);
    const int kc = (lane & 3) * 8;
    const u16* Aq0 = A + (size_t)(bm + rA0) * Kd + kc;
    const u16* Aq1 = A + (size_t)(bm + rA1) * Kd + kc;
    const u16* Bq  = Bt + (size_t)(bn + rB) * Kd + kc;
    u16* lA0 = As + (w * 2 + 0) * 512;
    u16* lA1 = As + (w * 2 + 1) * 512;
    u16* lB  = Bs + w * 512;

    f32x4 acc[4][2] = {};
    const int fm = (lane & 15);
    const int q8 = (lane >> 4) * 8;

    for (int k0 = 0; k0 < Kd; k0 += 32) {
        gload_lds16(Aq0 + k0, lA0);
        gload_lds16(Aq1 + k0, lA1);
        gload_lds16(Bq + k0, lB);
        __syncthreads();
        bf16x8 af[4], bf[2];
        #pragma unroll
        for (int i = 0; i < 4; ++i)
            af[i] = *(const bf16x8*)&As[(wm * 64 + i * 16 + fm) * 32 + q8];
        #pragma unroll
        for (int j = 0; j < 2; ++j)
            bf[j] = *(const bf16x8*)&Bs[(wn * 32 + j * 16 + fm) * 32 + q8];
        #pragma unroll
        for (int i = 0; i < 4; ++i)
            #pragma unroll
            for (int j = 0; j < 2; ++j)
                acc[i][j] = __builtin_amdgcn_mfma_f32_16x16x32_bf16(af[i], bf[j], acc[i][j], 0, 0, 0);
        __syncthreads();
    }

    const int crow0 = bm + wm * 64 + (lane >> 4) * 4;
    const int ccol0 = bn + wn * 32 + (lane & 15);
    #pragma unroll
    for (int i = 0; i < 4; ++i)
        #pragma unroll
        for (int r = 0; r < 4; ++r) {
            const int row = crow0 + i * 16 + r;
            #pragma unroll
            for (int j = 0; j < 2; ++j) {
                const int col = ccol0 + j * 16;
                C[(size_t)row * N + col] = acc[i][j][r] + resid[(size_t)row * N + col];
            }
        }
}

// -------------------------------------------------------------- conv+silu ---
// u (bf16) = silu(depthwise-causal-conv(xz[:, :DI])); xz bf16; 4 ch/thread.
__global__ __launch_bounds__(256) void conv_silu_kernel(const u16* __restrict__ xz,
                                                        const float* __restrict__ cw,
                                                        const float* __restrict__ cb,
                                                        u16* __restrict__ u) {
    const int idx4 = blockIdx.x * 256 + threadIdx.x;   // over ROWS*DI/4
    const int d4 = (idx4 & (DI_SZ / 4 - 1)) * 4;
    const int r = idx4 >> 9;          // / (DI/4)
    const int t = r & (L_SZ - 1);
    float acc[4];
    float4 cbv = *(const float4*)(cb + d4);
    acc[0] = cbv.x; acc[1] = cbv.y; acc[2] = cbv.z; acc[3] = cbv.w;
    float wv[4][4];
    #pragma unroll
    for (int j = 0; j < 4; ++j) *(float4*)wv[j] = *(const float4*)(cw + (d4 + j) * 4);
    const u16* base = xz + (size_t)r * (2 * DI_SZ) + d4;
    #pragma unroll
    for (int k = 0; k < 4; ++k) {
        int tt = t - 3 + k;
        if (tt >= 0) {
            ushort4 xv = *(const ushort4*)(base + (ptrdiff_t)(k - 3) * (2 * DI_SZ));
            acc[0] += bf2f(xv.x) * wv[0][k];
            acc[1] += bf2f(xv.y) * wv[1][k];
            acc[2] += bf2f(xv.z) * wv[2][k];
            acc[3] += bf2f(xv.w) * wv[3][k];
        }
    }
    ushort4 o;
    o.x = f2bf(acc[0] / (1.0f + __expf(-acc[0])));
    o.y = f2bf(acc[1] / (1.0f + __expf(-acc[1])));
    o.z = f2bf(acc[2] / (1.0f + __expf(-acc[2])));
    o.w = f2bf(acc[3] / (1.0f + __expf(-acc[3])));
    *(ushort4*)(u + (size_t)r * DI_SZ + d4) = o;
}

// ------------------------------------------------------------------ x_proj ---
// xdbl[4096][96] += u[4096][2048] @ Wt_x[96][2048]^T ; split-K=8, MFMA.
__global__ __launch_bounds__(256) void xproj_mfma(const u16* __restrict__ ubf,
                                                  const u16* __restrict__ Wt,
                                                  float* __restrict__ xdbl) {
    const int lane = threadIdx.x & 63;
    const int w = threadIdx.x >> 6;
    const int m0 = blockIdx.x * 64 + w * 16;
    const int k0 = blockIdx.y * 256;
    const int fr = lane & 15;
    const int q8 = (lane >> 4) * 8;
    const u16* Arow = ubf + (size_t)(m0 + fr) * DI_SZ + k0 + q8;
    const u16* Brow = Wt + (size_t)fr * DI_SZ + k0 + q8;
    f32x4 acc[6] = {};
    #pragma unroll 2
    for (int kk = 0; kk < 256; kk += 32) {
        bf16x8 a = *(const bf16x8*)(Arow + kk);
        #pragma unroll
        for (int j = 0; j < 6; ++j) {
            bf16x8 b = *(const bf16x8*)(Brow + (size_t)(j * 16) * DI_SZ + kk);
            acc[j] = __builtin_amdgcn_mfma_f32_16x16x32_bf16(a, b, acc[j], 0, 0, 0);
        }
    }
    const int row0 = m0 + (lane >> 4) * 4;
    const int col = lane & 15;
    #pragma unroll
    for (int j = 0; j < 6; ++j)
        #pragma unroll
        for (int r = 0; r < 4; ++r)
            atomicAdd(&xdbl[(size_t)(row0 + r) * 96 + j * 16 + col], acc[j][r]);
}

// --------------------------------------------------- xdbl dt-slice -> bf16 --
__global__ __launch_bounds__(256) void dtslice_bf16_kernel(const float* __restrict__ xdbl,
                                                           u16* __restrict__ out) {
    const int idx = blockIdx.x * 256 + threadIdx.x;   // over ROWS*64
    const int r = idx >> 6, k = idx & 63;
    out[idx] = f2bf(xdbl[(size_t)r * 96 + k]);
}

// -------------------------------------------------- dt_proj (MFMA) ----------
// dt = bf16(softplus(Axd[4096][64] @ Wt[2048][64]^T + bias)). 128x128, K=64.
__global__ __launch_bounds__(256, 2) void dtproj_mfma(const u16* __restrict__ Axd,
                                                      const u16* __restrict__ Wt,
                                                      const float* __restrict__ bias,
                                                      u16* __restrict__ dt) {
    __shared__ __align__(16) u16 As[128 * 64];
    __shared__ __align__(16) u16 Bs[128 * 64];
    const int tid = threadIdx.x;
    const int lane = tid & 63;
    const int w = tid >> 6;
    const int wm = w >> 1, wn = w & 1;
    const int bm = blockIdx.y * 128, bn = blockIdx.x * 128;

    #pragma unroll
    for (int q = 0; q < 4; ++q) {
        const int rr = (w * 4 + q) * 8 + (lane >> 3);
        const int kc = (lane & 7) * 8;
        gload_lds16(Axd + (size_t)(bm + rr) * 64 + kc, As + (w * 4 + q) * 512);
        gload_lds16(Wt  + (size_t)(bn + rr) * 64 + kc, Bs + (w * 4 + q) * 512);
    }
    __syncthreads();

    const int fm = lane & 15;
    const int q8 = (lane >> 4) * 8;
    f32x4 acc[4][4] = {};
    #pragma unroll
    for (int k0 = 0; k0 < 64; k0 += 32) {
        bf16x8 af[4], bf[4];
        #pragma unroll
        for (int i = 0; i < 4; ++i)
            af[i] = *(const bf16x8*)&As[(wm * 64 + i * 16 + fm) * 64 + k0 + q8];
        #pragma unroll
        for (int j = 0; j < 4; ++j)
            bf[j] = *(const bf16x8*)&Bs[(wn * 64 + j * 16 + fm) * 64 + k0 + q8];
        #pragma unroll
        for (int i = 0; i < 4; ++i)
            #pragma unroll
            for (int j = 0; j < 4; ++j)
                acc[i][j] = __builtin_amdgcn_mfma_f32_16x16x32_bf16(af[i], bf[j], acc[i][j], 0, 0, 0);
    }

    const int crow0 = bm + wm * 64 + (lane >> 4) * 4;
    const int ccol0 = bn + wn * 64 + (lane & 15);
    #pragma unroll
    for (int j = 0; j < 4; ++j) {
        const int col = ccol0 + j * 16;
        const float b = bias[col];
        #pragma unroll
        for (int i = 0; i < 4; ++i)
            #pragma unroll
            for (int r = 0; r < 4; ++r) {
                const int row = crow0 + i * 16 + r;
                float v = acc[i][j][r] + b;
                float sp = (v > 20.0f) ? v : log1pf(__expf(v));
                dt[(size_t)row * DI_SZ + col] = f2bf(sp);
            }
    }
}

// ------------------------------------------------- scan pass 1: local chunks -
__global__ __launch_bounds__(64) void scan_pass1(const u16* __restrict__ dt,
                                                 const u16* __restrict__ u,
                                                 const float* __restrict__ xdbl,
                                                 const float* __restrict__ A_log,
                                                 float* __restrict__ P,
                                                 float* __restrict__ S) {
    const int c     = blockIdx.x & (NCH - 1);
    const int dtile = (blockIdx.x >> 5) & 31;
    const int b     = blockIdx.x >> 10;
    const int d     = dtile * 64 + threadIdx.x;
    float A[N_SZ];
    #pragma unroll
    for (int n = 0; n < N_SZ; ++n) A[n] = -expf(A_log[d * N_SZ + n]);
    __shared__ __align__(16) float bs[CH][16];
    const size_t rbase = (size_t)b * L_SZ + c * CH;
    for (int idx = threadIdx.x; idx < CH * 16; idx += 64) {
        int tt = idx >> 4, j = idx & 15;
        bs[tt][j] = xdbl[(rbase + tt) * 96 + 64 + j];
    }
    __syncthreads();
    float h[N_SZ] = {};
    float p[N_SZ];
    #pragma unroll
    for (int n = 0; n < N_SZ; ++n) p[n] = 1.0f;
    float dtv = bf2f(dt[rbase * DI_SZ + d]);
    float uv  = bf2f(u[rbase * DI_SZ + d]);
    for (int ti = 0; ti < CH; ++ti) {
        float dtn = 0.0f, un = 0.0f;
        if (ti + 1 < CH) {
            dtn = bf2f(dt[(rbase + ti + 1) * DI_SZ + d]);
            un  = bf2f(u[(rbase + ti + 1) * DI_SZ + d]);
        }
        const float dtu = dtv * uv;
        float bv[N_SZ];
        #pragma unroll
        for (int q = 0; q < 4; ++q) *(float4*)&bv[q * 4] = *(const float4*)&bs[ti][q * 4];
        #pragma unroll
        for (int n = 0; n < N_SZ; ++n) {
            float dA = __expf(dtv * A[n]);
            p[n] *= dA;
            h[n] = dA * h[n] + dtu * bv[n];
        }
        dtv = dtn; uv = un;
    }
    const size_t base = (size_t)c * PS_SLICE + ((size_t)b * DI_SZ + d) * N_SZ;
    #pragma unroll
    for (int q = 0; q < 4; ++q) {
        *(float4*)&P[base + q * 4] = make_float4(p[q*4], p[q*4+1], p[q*4+2], p[q*4+3]);
        *(float4*)&S[base + q * 4] = make_float4(h[q*4], h[q*4+1], h[q*4+2], h[q*4+3]);
    }
}

// --------------------------------------- scan pass 2: scan over chunks ------
__global__ __launch_bounds__(256) void scan_pass2(float* __restrict__ P,
                                                  float* __restrict__ S) {
    const int i = blockIdx.x * 256 + threadIdx.x;   // [0, PS_SLICE)
    float h = 0.0f;
    for (int c = 0; c < NCH; ++c) {
        const size_t idx = (size_t)c * PS_SLICE + i;
        const float p = P[idx];
        const float s = S[idx];
        S[idx] = h;
        h = p * h + s;
    }
}

// ----------------------------------- scan pass 3: replay with correct h0 ----
__global__ __launch_bounds__(64) void scan_pass3(const u16* __restrict__ dt,
                                                 const u16* __restrict__ u,
                                                 const u16* __restrict__ xz,
                                                 const float* __restrict__ xdbl,
                                                 const float* __restrict__ A_log,
                                                 const float* __restrict__ Dw,
                                                 const float* __restrict__ H0,
                                                 u16* __restrict__ y) {
    const int c     = blockIdx.x & (NCH - 1);
    const int dtile = (blockIdx.x >> 5) & 31;
    const int b     = blockIdx.x >> 10;
    const int d     = dtile * 64 + threadIdx.x;
    float A[N_SZ];
    #pragma unroll
    for (int n = 0; n < N_SZ; ++n) A[n] = -expf(A_log[d * N_SZ + n]);
    const float Dd = Dw[d];
    __shared__ __align__(16) float bc[CH][32];   // B (0..15) | C (16..31)
    const size_t rbase = (size_t)b * L_SZ + c * CH;
    for (int idx = threadIdx.x; idx < CH * 32; idx += 64) {
        int tt = idx >> 5, j = idx & 31;
        bc[tt][j] = xdbl[(rbase + tt) * 96 + 64 + j];
    }
    __syncthreads();
    float h[N_SZ];
    const size_t hbase = (size_t)c * PS_SLICE + ((size_t)b * DI_SZ + d) * N_SZ;
    #pragma unroll
    for (int q = 0; q < 4; ++q) *(float4*)&h[q * 4] = *(const float4*)&H0[hbase + q * 4];
    float dtv = bf2f(dt[rbase * DI_SZ + d]);
    float uv  = bf2f(u[rbase * DI_SZ + d]);
    float zv  = bf2f(xz[rbase * (2 * DI_SZ) + DI_SZ + d]);
    for (int ti = 0; ti < CH; ++ti) {
        float dtn = 0.0f, un = 0.0f, zn = 0.0f;
        if (ti + 1 < CH) {
            const size_t rn = rbase + ti + 1;
            dtn = bf2f(dt[rn * DI_SZ + d]);
            un  = bf2f(u[rn * DI_SZ + d]);
            zn  = bf2f(xz[rn * (2 * DI_SZ) + DI_SZ + d]);
        }
        const float dtu = dtv * uv;
        float bv[32];
        #pragma unroll
        for (int q = 0; q < 8; ++q) *(float4*)&bv[q * 4] = *(const float4*)&bc[ti][q * 4];
        float yv = 0.0f;
        #pragma unroll
        for (int n = 0; n < N_SZ; ++n) {
            float dA = __expf(dtv * A[n]);
            h[n] = dA * h[n] + dtu * bv[n];
            yv += h[n] * bv[16 + n];
        }
        const float sz = zv / (1.0f + __expf(-zv));
        y[(rbase + ti) * DI_SZ + d] = f2bf((yv + uv * Dd) * sz);
        dtv = dtn; uv = un; zv = zn;
    }
}

// ---------------------------------------------------------------- launcher ---
extern "C" void kernel_launch(void* const* d_in, const int* in_sizes, int n_in,
                              void* d_out, int out_size, void* d_ws, size_t ws_size,
                              hipStream_t stream) {
    const float* x         = (const float*)d_in[0];
    // d_in[1] hormone_vectors: unused by reference
    const float* norm_w    = (const float*)d_in[2];
    const float* in_proj_w = (const float*)d_in[3];
    const float* conv_w    = (const float*)d_in[4];
    const float* conv_b    = (const float*)d_in[5];
    const float* x_proj_w  = (const float*)d_in[6];
    const float* dt_proj_w = (const float*)d_in[7];
    const float* dt_proj_b = (const float*)d_in[8];
    const float* A_log     = (const float*)d_in[9];
    const float* Dw        = (const float*)d_in[10];
    const float* out_proj_w= (const float*)d_in[11];
    float* out = (float*)d_out;

    char* ws = (char*)d_ws;
    size_t off = 0;
    // h (bf16 [4096][1024]) aliases y (bf16 [4096][2048]); h dead before scan.
    u16* y      = (u16*)(ws + off);    off += (size_t)ROWS * DI_SZ * 2;       // 16.8 MB
    u16* h      = y;
    u16* xz     = (u16*)(ws + off);    off += (size_t)ROWS * 2 * DI_SZ * 2;   // 33.5 MB
    u16* u      = (u16*)(ws + off);    off += (size_t)ROWS * DI_SZ * 2;       // 16.8 MB
    float* xdbl = (float*)(ws + off);  off += (size_t)ROWS * 96 * 4;          // 1.6 MB
    u16* dt     = (u16*)(ws + off);    off += (size_t)ROWS * DI_SZ * 2;       // 16.8 MB
    float* P    = (float*)(ws + off);  off += (size_t)NCH * PS_SLICE * 4;     // 8.4 MB
    float* S    = (float*)(ws + off);  off += (size_t)NCH * PS_SLICE * 4;     // 8.4 MB
    u16* ipw_t  = (u16*)(ws + off);    off += (size_t)(2 * DI_SZ) * DM_SZ * 2;// 16.8 MB
    u16* opw_t  = (u16*)(ws + off);    off += (size_t)DM_SZ * DI_SZ * 2;      // 4.2 MB
    u16* xpw_t  = (u16*)(ws + off);    off += (size_t)96 * DI_SZ * 2;         // 0.4 MB
    u16* dtw_t  = (u16*)(ws + off);    off += (size_t)DI_SZ * R_SZ * 2;       // 0.26 MB
    u16* xdbl_bf= (u16*)(ws + off);    off += (size_t)ROWS * R_SZ * 2;        // 0.5 MB
    (void)ws_size; (void)out_size; (void)n_in; (void)in_sizes;

    // 1. rmsnorm -> h (bf16)
    rmsnorm_kernel<<<ROWS, 256, 0, stream>>>(x, norm_w, h);
    // 1b. all weight transposes (bf16, [N][K]) in one dispatch
    transpose_all<<<6464, 256, 0, stream>>>(in_proj_w, ipw_t, out_proj_w, opw_t,
                                            x_proj_w, xpw_t, dt_proj_w, dtw_t);
    // 2. xz = bf16(h @ in_proj_w)   (4096 x 4096 x 1024, bf16 MFMA)
    mfma_gemm_xz<<<dim3(2 * DI_SZ / 128, ROWS / 128), 256, 0, stream>>>(
        h, ipw_t, xz, ROWS, 2 * DI_SZ, DM_SZ);
    // 3. u = silu(conv(xz[:, :DI])) -> bf16
    conv_silu_kernel<<<(ROWS * DI_SZ / 4) / 256, 256, 0, stream>>>(xz, conv_w, conv_b, u);
    // 4. xdbl = u @ x_proj_w  (4096 x 96 x 2048, MFMA split-K + atomics)
    hipMemsetAsync(xdbl, 0, (size_t)ROWS * 96 * 4, stream);
    xproj_mfma<<<dim3(ROWS / 64, 8), 256, 0, stream>>>(u, xpw_t, xdbl);
    // 5. dt = bf16(softplus(xdbl[:, :64] @ dt_proj_w + b))  (MFMA)
    dtslice_bf16_kernel<<<(ROWS * R_SZ) / 256, 256, 0, stream>>>(xdbl, xdbl_bf);
    dtproj_mfma<<<dim3(DI_SZ / 128, ROWS / 128), 256, 0, stream>>>(
        xdbl_bf, dtw_t, dt_proj_b, dt);
    // 6. chunked selective scan -> y (bf16)
    scan_pass1<<<B_SZ * 32 * NCH, 64, 0, stream>>>(dt, u, xdbl, A_log, P, S);
    scan_pass2<<<PS_SLICE / 256, 256, 0, stream>>>(P, S);
    scan_pass3<<<B_SZ * 32 * NCH, 64, 0, stream>>>(dt, u, xz, xdbl, A_log, Dw, S, y);
    // 7. out = x + y @ out_proj_w  (4096 x 1024 x 2048, bf16 MFMA, 128x64 tiles)
    mfma_gemm_rn<<<dim3(DM_SZ / 64, ROWS / 128), 256, 0, stream>>>(
        y, opw_t, out, x, ROWS, DM_SZ, DI_SZ);
}